// Round 1
// baseline (412.655 us; speedup 1.0000x reference)
//
#include <hip/hip_runtime.h>
#include <cstdint>

typedef unsigned short u16;
typedef __attribute__((ext_vector_type(8))) short bf16x8;
typedef __attribute__((ext_vector_type(4))) float f32x4;

static __device__ __forceinline__ float b2f(u16 u) {
  union { unsigned int i; float f; } v; v.i = ((unsigned int)u) << 16; return v.f;
}
static __device__ __forceinline__ u16 f2b(float f) {
  union { float f; unsigned int i; } v; v.f = f;
  unsigned int r = (v.i + 0x7FFFu + ((v.i >> 16) & 1u)) >> 16;
  return (u16)r;
}
static __device__ __forceinline__ void load_lds16(const void* g, void* l) {
  __builtin_amdgcn_global_load_lds((const __attribute__((address_space(1))) void*)g,
                                   (__attribute__((address_space(3))) void*)l, 16, 0, 0);
}

// ---------------- pack x (fp32 -> bf16), 4 elems/thread ----------------
__global__ void pack_x_kernel(const float* __restrict__ x, u16* __restrict__ xb) {
  int idx = blockIdx.x * 256 + threadIdx.x;
  float4 v = ((const float4*)x)[idx];
  unsigned long long pk = (unsigned long long)f2b(v.x)
                        | ((unsigned long long)f2b(v.y) << 16)
                        | ((unsigned long long)f2b(v.z) << 32)
                        | ((unsigned long long)f2b(v.w) << 48);
  ((unsigned long long*)xb)[idx] = pk;
}

// ---------------- transpose fp32 [R][C] -> bf16 [C][R] ----------------
__global__ void transpose_kernel(const float* __restrict__ src, u16* __restrict__ dst,
                                 int R, int C) {
  __shared__ float tile[32][33];
  int tx = threadIdx.x & 31, ty = threadIdx.x >> 5;
  int c0 = blockIdx.x * 32, r0 = blockIdx.y * 32;
#pragma unroll
  for (int i = 0; i < 4; ++i)
    tile[ty + i * 8][tx] = src[(size_t)(r0 + ty + i * 8) * C + c0 + tx];
  __syncthreads();
#pragma unroll
  for (int i = 0; i < 4; ++i)
    dst[(size_t)(c0 + ty + i * 8) * R + r0 + tx] = f2b(tile[tx][ty + i * 8]);
}

// ---------------- RoPE tables: [T][64] cos/sin ----------------
__global__ void rope_tables_kernel(float* __restrict__ cosT, float* __restrict__ sinT) {
  int idx = blockIdx.x * 256 + threadIdx.x;  // T*64
  int t = idx >> 6, i = idx & 63;
  float inv = powf(10000.0f, -(float)i * (1.0f / 64.0f));
  float a = (float)t * inv;
  cosT[idx] = cosf(a);
  sinT[idx] = sinf(a);
}

// ---------------- GEMM: C[M][N] = A[M][K] * BT[N][K]^T  (bf16 in, OUTF=0 bf16 / 1 fp32 out)
template <int OUTF>
__global__ __launch_bounds__(256) void gemm_bt_kernel(const u16* __restrict__ A,
                                                      const u16* __restrict__ BT,
                                                      void* __restrict__ Cv,
                                                      int M, int N, int K) {
  __shared__ __align__(16) u16 lA[128 * 64];
  __shared__ __align__(16) u16 lB[128 * 64];
  const int tid = threadIdx.x;
  const int wave = tid >> 6, lane = tid & 63;
  const int wr = wave >> 1, wc = wave & 1;
  const int row0 = blockIdx.y * 128, col0 = blockIdx.x * 128;
  f32x4 acc[4][4];
#pragma unroll
  for (int m = 0; m < 4; ++m)
#pragma unroll
    for (int n = 0; n < 4; ++n) acc[m][n] = (f32x4){0.f, 0.f, 0.f, 0.f};
  const int rb = wave * 32;
  const int lrow = lane >> 3, lk = (lane & 7) * 8;
  for (int k0 = 0; k0 < K; k0 += 64) {
    __syncthreads();
    const u16* sA = A + (size_t)(row0 + rb + lrow) * K + k0 + lk;
    const u16* sB = BT + (size_t)(col0 + rb + lrow) * K + k0 + lk;
#pragma unroll
    for (int i = 0; i < 4; ++i) {
      load_lds16(sA + (size_t)i * 8 * K, &lA[(rb + i * 8) * 64]);
      load_lds16(sB + (size_t)i * 8 * K, &lB[(rb + i * 8) * 64]);
    }
    __syncthreads();
#pragma unroll
    for (int ks = 0; ks < 2; ++ks) {
      bf16x8 af[4], bfr[4];
#pragma unroll
      for (int m = 0; m < 4; ++m)
        af[m] = *(const bf16x8*)&lA[(wr * 64 + m * 16 + (lane & 15)) * 64 + ks * 32 + (lane >> 4) * 8];
#pragma unroll
      for (int n = 0; n < 4; ++n)
        bfr[n] = *(const bf16x8*)&lB[(wc * 64 + n * 16 + (lane & 15)) * 64 + ks * 32 + (lane >> 4) * 8];
#pragma unroll
      for (int m = 0; m < 4; ++m)
#pragma unroll
        for (int n = 0; n < 4; ++n)
          acc[m][n] = __builtin_amdgcn_mfma_f32_16x16x32_bf16(af[m], bfr[n], acc[m][n], 0, 0, 0);
    }
  }
  const int rbase = row0 + wr * 64 + ((lane >> 4) << 2);
  const int cbase = col0 + wc * 64 + (lane & 15);
#pragma unroll
  for (int m = 0; m < 4; ++m)
#pragma unroll
    for (int n = 0; n < 4; ++n)
#pragma unroll
      for (int j = 0; j < 4; ++j) {
        size_t off = (size_t)(rbase + m * 16 + j) * N + cbase + n * 16;
        if (OUTF == 0) ((u16*)Cv)[off] = f2b(acc[m][n][j]);
        else           ((float*)Cv)[off] = acc[m][n][j];
      }
}

// ---------------- RoPE in-place on Q,K columns of QKV [4096][3072] ----------------
__global__ void rope_kernel(u16* __restrict__ QKV, const float* __restrict__ cosT,
                            const float* __restrict__ sinT) {
  int idx = blockIdx.x * 256 + threadIdx.x;  // 4096*1280
  int row = idx / 1280;
  int rem = idx - row * 1280;
  int t = row & 2047;
  int i = rem & 63;
  int col;
  if (rem < 1024) col = (rem >> 6) * 128 + 2 * i;
  else { int r2 = rem - 1024; col = 2048 + (r2 >> 6) * 128 + 2 * i; }
  float c = cosT[t * 64 + i], s = sinT[t * 64 + i];
  size_t o = (size_t)row * 3072 + col;
  float x1 = b2f(QKV[o]), x2 = b2f(QKV[o + 1]);
  QKV[o]     = f2b(x1 * c - x2 * s);
  QKV[o + 1] = f2b(x1 * s + x2 * c);
}

// ---------------- fused SWA+meta GQA attention ----------------
// Q/K/V read from QKV [B*T][3072] (Q: h*128, K: 2048+kv*128, V: 2560+kv*128)
// out AO [B*T][2048] bf16 (col = h*128+dh)
__global__ __launch_bounds__(256) void attn_kernel(const u16* __restrict__ QKV,
                                                   u16* __restrict__ AO) {
  __shared__ __align__(16) u16 lVt[128 * 72];     // [dh][key], padded
  __shared__ __align__(16) u16 lP[4][16 * 72];    // per-wave P tile [q][key]
  const int tid = threadIdx.x, wave = tid >> 6, lane = tid & 63;
  const int bh = blockIdx.y, b = bh >> 4, h = bh & 15, kv = h >> 2;
  const int q0 = blockIdx.x * 64;
  const int qw = q0 + wave * 16;
  const size_t rowbase = (size_t)(b * 2048) * 3072;
  const u16* Qb = QKV + rowbase + h * 128;
  const u16* Kb = QKV + rowbase + 2048 + kv * 128;
  const u16* Vp = QKV + rowbase + 2560 + kv * 128;

  bf16x8 qf[4];
  {
    const u16* qs = Qb + (size_t)(qw + (lane & 15)) * 3072 + (lane >> 4) * 8;
#pragma unroll
    for (int s = 0; s < 4; ++s) qf[s] = *(const bf16x8*)(qs + s * 32);
  }
  f32x4 oacc[8];
#pragma unroll
  for (int n = 0; n < 8; ++n) oacc[n] = (f32x4){0.f, 0.f, 0.f, 0.f};
  float m_run[4] = {-1e30f, -1e30f, -1e30f, -1e30f};
  float l_run[4] = {0.f, 0.f, 0.f, 0.f};

  const int qt = q0 >> 6;
  const int kt_lo = (q0 > 1023) ? ((q0 - 1023) >> 6) : 0;
  const int nt = (qt - kt_lo + 1) + (kt_lo > 0 ? 1 : 0);
  const int qrb = qw + ((lane >> 4) << 2);

  for (int it = 0; it < nt; ++it) {
    const int kt = (kt_lo > 0) ? (it == 0 ? 0 : kt_lo + it - 1) : it;
    const int kb = kt * 64;
    __syncthreads();
    // stage V tile transposed: lVt[dh][key]
#pragma unroll
    for (int p = 0; p < 4; ++p) {
      const int key = p * 16 + (tid >> 4);
      const int d0 = (tid & 15) * 8;
      bf16x8 vv = *(const bf16x8*)(Vp + (size_t)(kb + key) * 3072 + d0);
#pragma unroll
      for (int e = 0; e < 8; ++e) lVt[(d0 + e) * 72 + key] = (u16)vv[e];
    }
    __syncthreads();
    // S = Q K^T (16q x 64key per wave)
    f32x4 sc[4];
#pragma unroll
    for (int ct = 0; ct < 4; ++ct) {
      f32x4 s = (f32x4){0.f, 0.f, 0.f, 0.f};
      const u16* kptr = Kb + (size_t)(kb + ct * 16 + (lane & 15)) * 3072 + (lane >> 4) * 8;
#pragma unroll
      for (int ss = 0; ss < 4; ++ss) {
        bf16x8 kf = *(const bf16x8*)(kptr + ss * 32);
        s = __builtin_amdgcn_mfma_f32_16x16x32_bf16(qf[ss], kf, s, 0, 0, 0);
      }
      sc[ct] = s;
    }
    const float scale = 0.08838834764831845f;  // 1/sqrt(128)
#pragma unroll
    for (int ct = 0; ct < 4; ++ct) {
      const int key = kb + ct * 16 + (lane & 15);
#pragma unroll
      for (int j = 0; j < 4; ++j) {
        const int q = qrb + j;
        float sv = sc[ct][j] * scale;
        bool ok = (key < 16) || (key <= q && (q - key) < 1024);
        sc[ct][j] = ok ? sv : -1e30f;
      }
    }
    float mt[4], rs[4], alpha[4];
#pragma unroll
    for (int j = 0; j < 4; ++j)
      mt[j] = fmaxf(fmaxf(sc[0][j], sc[1][j]), fmaxf(sc[2][j], sc[3][j]));
#pragma unroll
    for (int off = 1; off < 16; off <<= 1)
#pragma unroll
      for (int j = 0; j < 4; ++j)
        mt[j] = fmaxf(mt[j], __shfl_xor(mt[j], off, 16));
#pragma unroll
    for (int j = 0; j < 4; ++j) {
      float mn = fmaxf(m_run[j], mt[j]);
      alpha[j] = __expf(m_run[j] - mn);
      m_run[j] = mn;
    }
#pragma unroll
    for (int ct = 0; ct < 4; ++ct)
#pragma unroll
      for (int j = 0; j < 4; ++j)
        sc[ct][j] = __expf(sc[ct][j] - m_run[j]);
#pragma unroll
    for (int j = 0; j < 4; ++j)
      rs[j] = (sc[0][j] + sc[1][j]) + (sc[2][j] + sc[3][j]);
#pragma unroll
    for (int off = 1; off < 16; off <<= 1)
#pragma unroll
      for (int j = 0; j < 4; ++j)
        rs[j] += __shfl_xor(rs[j], off, 16);
#pragma unroll
    for (int j = 0; j < 4; ++j)
      l_run[j] = l_run[j] * alpha[j] + rs[j];
#pragma unroll
    for (int n = 0; n < 8; ++n)
#pragma unroll
      for (int j = 0; j < 4; ++j)
        oacc[n][j] *= alpha[j];
    // write P tile (per-wave, intra-wave LDS ordering is sufficient)
    u16* Pw = &lP[wave][0];
#pragma unroll
    for (int ct = 0; ct < 4; ++ct)
#pragma unroll
      for (int j = 0; j < 4; ++j)
        Pw[(((lane >> 4) << 2) + j) * 72 + ct * 16 + (lane & 15)] = f2b(sc[ct][j]);
    // O += P V
#pragma unroll
    for (int kss = 0; kss < 2; ++kss) {
      bf16x8 pa = *(const bf16x8*)&Pw[(lane & 15) * 72 + kss * 32 + (lane >> 4) * 8];
#pragma unroll
      for (int n = 0; n < 8; ++n) {
        bf16x8 vf = *(const bf16x8*)&lVt[(n * 16 + (lane & 15)) * 72 + kss * 32 + (lane >> 4) * 8];
        oacc[n] = __builtin_amdgcn_mfma_f32_16x16x32_bf16(pa, vf, oacc[n], 0, 0, 0);
      }
    }
  }
#pragma unroll
  for (int j = 0; j < 4; ++j) {
    const float inv = 1.0f / l_run[j];
    const size_t rowo = (size_t)(b * 2048 + qrb + j) * 2048 + h * 128;
#pragma unroll
    for (int n = 0; n < 8; ++n)
      AO[rowo + n * 16 + (lane & 15)] = f2b(oacc[n][j] * inv);
  }
}

extern "C" void kernel_launch(void* const* d_in, const int* in_sizes, int n_in,
                              void* d_out, int out_size, void* d_ws, size_t ws_size,
                              hipStream_t stream) {
  (void)in_sizes; (void)n_in; (void)out_size; (void)ws_size;
  const float* x  = (const float*)d_in[0];
  const float* wq = (const float*)d_in[1];
  const float* wk = (const float*)d_in[2];
  const float* wv = (const float*)d_in[3];
  const float* wo = (const float*)d_in[4];
  float* out = (float*)d_out;

  // workspace carve (bytes ~81 MB total)
  u16* xb    = (u16*)d_ws;                         // [4096][2048]
  u16* wqkvT = xb    + (size_t)4096 * 2048;        // [3072][2048] (wq|wk|wv cols, N-major)
  u16* woT   = wqkvT + (size_t)3072 * 2048;        // [2048][2048]
  u16* QKV   = woT   + (size_t)2048 * 2048;        // [4096][3072]
  u16* AO    = QKV   + (size_t)4096 * 3072;        // [4096][2048]
  float* cosT = (float*)(AO + (size_t)4096 * 2048);  // [2048][64]
  float* sinT = cosT + 2048 * 64;

  pack_x_kernel<<<8192, 256, 0, stream>>>(x, xb);
  transpose_kernel<<<dim3(64, 64), 256, 0, stream>>>(wq, wqkvT, 2048, 2048);
  transpose_kernel<<<dim3(16, 64), 256, 0, stream>>>(wk, wqkvT + (size_t)2048 * 2048, 2048, 512);
  transpose_kernel<<<dim3(16, 64), 256, 0, stream>>>(wv, wqkvT + (size_t)2560 * 2048, 2048, 512);
  transpose_kernel<<<dim3(64, 64), 256, 0, stream>>>(wo, woT, 2048, 2048);
  rope_tables_kernel<<<512, 256, 0, stream>>>(cosT, sinT);
  gemm_bt_kernel<0><<<dim3(24, 32), 256, 0, stream>>>(xb, wqkvT, (void*)QKV, 4096, 3072, 2048);
  rope_kernel<<<20480, 256, 0, stream>>>(QKV, cosT, sinT);
  attn_kernel<<<dim3(32, 32), 256, 0, stream>>>(QKV, AO);
  gemm_bt_kernel<1><<<dim3(16, 32), 256, 0, stream>>>(AO, woT, (void*)out, 4096, 2048, 2048);
}

// Round 2
// 347.575 us; speedup vs baseline: 1.1872x; 1.1872x over previous
//
#include <hip/hip_runtime.h>
#include <cstdint>

typedef unsigned short u16;
typedef __attribute__((ext_vector_type(8))) short bf16x8;
typedef __attribute__((ext_vector_type(4))) float f32x4;

static __device__ __forceinline__ float b2f(u16 u) {
  union { unsigned int i; float f; } v; v.i = ((unsigned int)u) << 16; return v.f;
}
static __device__ __forceinline__ u16 f2b(float f) {
  union { float f; unsigned int i; } v; v.f = f;
  unsigned int r = (v.i + 0x7FFFu + ((v.i >> 16) & 1u)) >> 16;
  return (u16)r;
}
static __device__ __forceinline__ void load_lds16(const void* g, void* l) {
  __builtin_amdgcn_global_load_lds((const __attribute__((address_space(1))) void*)g,
                                   (__attribute__((address_space(3))) void*)l, 16, 0, 0);
}

// ---------------- pack x (fp32 -> bf16), 4 elems/thread ----------------
__global__ void pack_x_kernel(const float* __restrict__ x, u16* __restrict__ xb) {
  int idx = blockIdx.x * 256 + threadIdx.x;
  float4 v = ((const float4*)x)[idx];
  unsigned long long pk = (unsigned long long)f2b(v.x)
                        | ((unsigned long long)f2b(v.y) << 16)
                        | ((unsigned long long)f2b(v.z) << 32)
                        | ((unsigned long long)f2b(v.w) << 48);
  ((unsigned long long*)xb)[idx] = pk;
}

// ---------------- transpose fp32 [R][C] -> bf16 [C][R] ----------------
__global__ void transpose_kernel(const float* __restrict__ src, u16* __restrict__ dst,
                                 int R, int C) {
  __shared__ float tile[32][33];
  int tx = threadIdx.x & 31, ty = threadIdx.x >> 5;
  int c0 = blockIdx.x * 32, r0 = blockIdx.y * 32;
#pragma unroll
  for (int i = 0; i < 4; ++i)
    tile[ty + i * 8][tx] = src[(size_t)(r0 + ty + i * 8) * C + c0 + tx];
  __syncthreads();
#pragma unroll
  for (int i = 0; i < 4; ++i)
    dst[(size_t)(c0 + ty + i * 8) * R + r0 + tx] = f2b(tile[tx][ty + i * 8]);
}

// ---------------- V transpose: QKV V-cols -> Vt [b*4+kv][128 d][2048 t] ----------------
__global__ void v_transpose_kernel(const u16* __restrict__ QKV, u16* __restrict__ Vt) {
  __shared__ __align__(16) u16 tile[32][80];
  const int bkv = blockIdx.z;            // 0..7
  const int b = bkv >> 2, kv = bkv & 3;
  const int d0 = blockIdx.y * 32;        // 0..96
  const int t0 = blockIdx.x * 64;        // 0..1984
  const int tid = threadIdx.x;
  const int tr = tid >> 2, dc = tid & 3;
  bf16x8 vv = *(const bf16x8*)(QKV + (size_t)(b * 2048 + t0 + tr) * 3072 + 2560 + kv * 128 + d0 + dc * 8);
#pragma unroll
  for (int e = 0; e < 8; ++e) tile[dc * 8 + e][tr] = (u16)vv[e];
  __syncthreads();
  const int d = tid >> 3, tc = tid & 7;
  *(bf16x8*)(Vt + (size_t)(bkv * 128 + d0 + d) * 2048 + t0 + tc * 8) =
      *(const bf16x8*)&tile[d][tc * 8];
}

// ---------------- RoPE tables: [T][64] cos/sin ----------------
__global__ void rope_tables_kernel(float* __restrict__ cosT, float* __restrict__ sinT) {
  int idx = blockIdx.x * 256 + threadIdx.x;  // T*64
  int t = idx >> 6, i = idx & 63;
  float inv = powf(10000.0f, -(float)i * (1.0f / 64.0f));
  float a = (float)t * inv;
  cosT[idx] = cosf(a);
  sinT[idx] = sinf(a);
}

// ---------------- GEMM: C[M][N] = A[M][K] * BT[N][K]^T  (bf16 in, OUTF=0 bf16 / 1 fp32 out)
template <int OUTF>
__global__ __launch_bounds__(256) void gemm_bt_kernel(const u16* __restrict__ A,
                                                      const u16* __restrict__ BT,
                                                      void* __restrict__ Cv,
                                                      int M, int N, int K) {
  __shared__ __align__(16) u16 lA[128 * 64];
  __shared__ __align__(16) u16 lB[128 * 64];
  const int tid = threadIdx.x;
  const int wave = tid >> 6, lane = tid & 63;
  const int wr = wave >> 1, wc = wave & 1;
  const int row0 = blockIdx.y * 128, col0 = blockIdx.x * 128;
  f32x4 acc[4][4];
#pragma unroll
  for (int m = 0; m < 4; ++m)
#pragma unroll
    for (int n = 0; n < 4; ++n) acc[m][n] = (f32x4){0.f, 0.f, 0.f, 0.f};
  const int rb = wave * 32;
  const int lrow = lane >> 3, lk = (lane & 7) * 8;
  for (int k0 = 0; k0 < K; k0 += 64) {
    __syncthreads();
    const u16* sA = A + (size_t)(row0 + rb + lrow) * K + k0 + lk;
    const u16* sB = BT + (size_t)(col0 + rb + lrow) * K + k0 + lk;
#pragma unroll
    for (int i = 0; i < 4; ++i) {
      load_lds16(sA + (size_t)i * 8 * K, &lA[(rb + i * 8) * 64]);
      load_lds16(sB + (size_t)i * 8 * K, &lB[(rb + i * 8) * 64]);
    }
    __syncthreads();
#pragma unroll
    for (int ks = 0; ks < 2; ++ks) {
      bf16x8 af[4], bfr[4];
#pragma unroll
      for (int m = 0; m < 4; ++m)
        af[m] = *(const bf16x8*)&lA[(wr * 64 + m * 16 + (lane & 15)) * 64 + ks * 32 + (lane >> 4) * 8];
#pragma unroll
      for (int n = 0; n < 4; ++n)
        bfr[n] = *(const bf16x8*)&lB[(wc * 64 + n * 16 + (lane & 15)) * 64 + ks * 32 + (lane >> 4) * 8];
#pragma unroll
      for (int m = 0; m < 4; ++m)
#pragma unroll
        for (int n = 0; n < 4; ++n)
          acc[m][n] = __builtin_amdgcn_mfma_f32_16x16x32_bf16(af[m], bfr[n], acc[m][n], 0, 0, 0);
    }
  }
  const int rbase = row0 + wr * 64 + ((lane >> 4) << 2);
  const int cbase = col0 + wc * 64 + (lane & 15);
#pragma unroll
  for (int m = 0; m < 4; ++m)
#pragma unroll
    for (int n = 0; n < 4; ++n)
#pragma unroll
      for (int j = 0; j < 4; ++j) {
        size_t off = (size_t)(rbase + m * 16 + j) * N + cbase + n * 16;
        if (OUTF == 0) ((u16*)Cv)[off] = f2b(acc[m][n][j]);
        else           ((float*)Cv)[off] = acc[m][n][j];
      }
}

// ---------------- RoPE in-place on Q,K columns of QKV [4096][3072] ----------------
__global__ void rope_kernel(u16* __restrict__ QKV, const float* __restrict__ cosT,
                            const float* __restrict__ sinT) {
  int idx = blockIdx.x * 256 + threadIdx.x;  // 4096*1280
  int row = idx / 1280;
  int rem = idx - row * 1280;
  int t = row & 2047;
  int i = rem & 63;
  int col;
  if (rem < 1024) col = (rem >> 6) * 128 + 2 * i;
  else { int r2 = rem - 1024; col = 2048 + (r2 >> 6) * 128 + 2 * i; }
  float c = cosT[t * 64 + i], s = sinT[t * 64 + i];
  size_t o = (size_t)row * 3072 + col;
  float x1 = b2f(QKV[o]), x2 = b2f(QKV[o + 1]);
  QKV[o]     = f2b(x1 * c - x2 * s);
  QKV[o + 1] = f2b(x1 * s + x2 * c);
}

// ---------------- fused SWA+meta GQA attention ----------------
// Q/K read from QKV [B*T][3072]; V from pre-transposed Vt [b*4+kv][128][2048].
// V tile staged with global_load_lds into linear LDS [128 d][64 k]; XOR slot
// swizzle applied on the GLOBAL source (linear LDS dest) and on the ds_read
// side (both-sides involution, T2/m173 pattern). Double-buffered, 1 barrier/tile.
__global__ __launch_bounds__(256) void attn_kernel(const u16* __restrict__ QKV,
                                                   const u16* __restrict__ Vt,
                                                   u16* __restrict__ AO) {
  __shared__ __align__(16) u16 lVt[2][128 * 64];  // [d][key-slot swizzled]
  __shared__ __align__(16) u16 lP[4][16 * 72];    // per-wave P tile [q][key]
  const int tid = threadIdx.x, wave = tid >> 6, lane = tid & 63;
  const int bh = blockIdx.y, b = bh >> 4, h = bh & 15, kv = h >> 2;
  const int q0 = blockIdx.x * 64;
  const int qw = q0 + wave * 16;
  const size_t rowbase = (size_t)(b * 2048) * 3072;
  const u16* Qb = QKV + rowbase + h * 128;
  const u16* Kb = QKV + rowbase + 2048 + kv * 128;
  // per-lane constant part of the staging source address:
  // lane stages 16B: row d = wave*32 + p*8 + (lane>>3), source key-chunk
  // c = (lane&7) ^ (d&7) = (lane&7) ^ (lane>>3)   (pre-swizzled source)
  const u16* vsrc = Vt + (size_t)(b * 4 + kv) * 128 * 2048
                  + (size_t)(wave * 32 + (lane >> 3)) * 2048
                  + ((lane & 7) ^ (lane >> 3)) * 8;

  bf16x8 qf[4];
  {
    const u16* qs = Qb + (size_t)(qw + (lane & 15)) * 3072 + (lane >> 4) * 8;
#pragma unroll
    for (int s = 0; s < 4; ++s) qf[s] = *(const bf16x8*)(qs + s * 32);
  }
  f32x4 oacc[8];
#pragma unroll
  for (int n = 0; n < 8; ++n) oacc[n] = (f32x4){0.f, 0.f, 0.f, 0.f};
  float m_run[4] = {-1e30f, -1e30f, -1e30f, -1e30f};
  float l_run[4] = {0.f, 0.f, 0.f, 0.f};

  const int qt = q0 >> 6;
  const int kt_lo = (q0 > 1023) ? ((q0 - 1023) >> 6) : 0;
  const int nt = (qt - kt_lo + 1) + (kt_lo > 0 ? 1 : 0);
  const int qrb = qw + ((lane >> 4) << 2);

  // prologue: stage tile 0 (kb = 0 in both branch cases) into buf 0
#pragma unroll
  for (int p = 0; p < 4; ++p)
    load_lds16(vsrc + (size_t)p * 8 * 2048, &lVt[0][(wave * 32 + p * 8) * 64]);

  int cur = 0;
  for (int it = 0; it < nt; ++it) {
    const int kt = (kt_lo > 0) ? (it == 0 ? 0 : kt_lo + it - 1) : it;
    const int kb = kt * 64;
    asm volatile("s_waitcnt vmcnt(0)" ::: "memory");
    __syncthreads();  // all waves' stage loads landed; buf[cur] ready

    // S = Q K^T (16q x 64key per wave), K frags straight from global (L2-resident)
    f32x4 sc[4];
#pragma unroll
    for (int ct = 0; ct < 4; ++ct) {
      f32x4 s = (f32x4){0.f, 0.f, 0.f, 0.f};
      const u16* kptr = Kb + (size_t)(kb + ct * 16 + (lane & 15)) * 3072 + (lane >> 4) * 8;
#pragma unroll
      for (int ss = 0; ss < 4; ++ss) {
        bf16x8 kf = *(const bf16x8*)(kptr + ss * 32);
        s = __builtin_amdgcn_mfma_f32_16x16x32_bf16(qf[ss], kf, s, 0, 0, 0);
      }
      sc[ct] = s;
    }

    // prefetch next V tile into the other buffer (lands by next barrier)
    if (it + 1 < nt) {
      const int kbn = ((kt_lo > 0) ? (kt_lo + it) : (it + 1)) * 64;
      u16* dst = &lVt[cur ^ 1][0];
#pragma unroll
      for (int p = 0; p < 4; ++p)
        load_lds16(vsrc + kbn + (size_t)p * 8 * 2048, dst + (wave * 32 + p * 8) * 64);
    }

    const float scale = 0.08838834764831845f;  // 1/sqrt(128)
#pragma unroll
    for (int ct = 0; ct < 4; ++ct) {
      const int key = kb + ct * 16 + (lane & 15);
#pragma unroll
      for (int j = 0; j < 4; ++j) {
        const int q = qrb + j;
        float sv = sc[ct][j] * scale;
        bool ok = (key < 16) || (key <= q && (q - key) < 1024);
        sc[ct][j] = ok ? sv : -1e30f;
      }
    }
    float mt[4], rs[4], alpha[4];
#pragma unroll
    for (int j = 0; j < 4; ++j)
      mt[j] = fmaxf(fmaxf(sc[0][j], sc[1][j]), fmaxf(sc[2][j], sc[3][j]));
#pragma unroll
    for (int off = 1; off < 16; off <<= 1)
#pragma unroll
      for (int j = 0; j < 4; ++j)
        mt[j] = fmaxf(mt[j], __shfl_xor(mt[j], off, 16));
#pragma unroll
    for (int j = 0; j < 4; ++j) {
      float mn = fmaxf(m_run[j], mt[j]);
      alpha[j] = __expf(m_run[j] - mn);
      m_run[j] = mn;
    }
#pragma unroll
    for (int ct = 0; ct < 4; ++ct)
#pragma unroll
      for (int j = 0; j < 4; ++j)
        sc[ct][j] = __expf(sc[ct][j] - m_run[j]);
#pragma unroll
    for (int j = 0; j < 4; ++j)
      rs[j] = (sc[0][j] + sc[1][j]) + (sc[2][j] + sc[3][j]);
#pragma unroll
    for (int off = 1; off < 16; off <<= 1)
#pragma unroll
      for (int j = 0; j < 4; ++j)
        rs[j] += __shfl_xor(rs[j], off, 16);
#pragma unroll
    for (int j = 0; j < 4; ++j)
      l_run[j] = l_run[j] * alpha[j] + rs[j];
#pragma unroll
    for (int n = 0; n < 8; ++n)
#pragma unroll
      for (int j = 0; j < 4; ++j)
        oacc[n][j] *= alpha[j];

    // write P tile (per-wave region; intra-wave ordering via lgkmcnt)
    u16* Pw = &lP[wave][0];
#pragma unroll
    for (int ct = 0; ct < 4; ++ct)
#pragma unroll
      for (int j = 0; j < 4; ++j)
        Pw[(((lane >> 4) << 2) + j) * 72 + ct * 16 + (lane & 15)] = f2b(sc[ct][j]);

    // O += P V  (V B-frags from swizzled LDS: slot = chunk ^ (row&7))
#pragma unroll
    for (int kss = 0; kss < 2; ++kss) {
      bf16x8 pa = *(const bf16x8*)&Pw[(lane & 15) * 72 + kss * 32 + (lane >> 4) * 8];
#pragma unroll
      for (int n = 0; n < 8; ++n) {
        const int vrow = n * 16 + (lane & 15);
        const int slot = (kss * 4 + (lane >> 4)) ^ (lane & 7);
        bf16x8 vf = *(const bf16x8*)&lVt[cur][vrow * 64 + slot * 8];
        oacc[n] = __builtin_amdgcn_mfma_f32_16x16x32_bf16(pa, vf, oacc[n], 0, 0, 0);
      }
    }
    cur ^= 1;
  }
#pragma unroll
  for (int j = 0; j < 4; ++j) {
    const float inv = 1.0f / l_run[j];
    const size_t rowo = (size_t)(b * 2048 + qrb + j) * 2048 + h * 128;
#pragma unroll
    for (int n = 0; n < 8; ++n)
      AO[rowo + n * 16 + (lane & 15)] = f2b(oacc[n][j] * inv);
  }
}

extern "C" void kernel_launch(void* const* d_in, const int* in_sizes, int n_in,
                              void* d_out, int out_size, void* d_ws, size_t ws_size,
                              hipStream_t stream) {
  (void)in_sizes; (void)n_in; (void)out_size; (void)ws_size;
  const float* x  = (const float*)d_in[0];
  const float* wq = (const float*)d_in[1];
  const float* wk = (const float*)d_in[2];
  const float* wv = (const float*)d_in[3];
  const float* wo = (const float*)d_in[4];
  float* out = (float*)d_out;

  // workspace carve (~68 MB)
  u16* xb    = (u16*)d_ws;                         // [4096][2048]
  u16* wqkvT = xb    + (size_t)4096 * 2048;        // [3072][2048]
  u16* woT   = wqkvT + (size_t)3072 * 2048;        // [2048][2048]
  u16* QKV   = woT   + (size_t)2048 * 2048;        // [4096][3072]
  u16* Vt    = QKV   + (size_t)4096 * 3072;        // [8][128][2048]
  float* cosT = (float*)(Vt + (size_t)8 * 128 * 2048);  // [2048][64]
  float* sinT = cosT + 2048 * 64;
  u16* AO = xb;  // alias: xb is dead after the QKV GEMM, AO written after it

  pack_x_kernel<<<8192, 256, 0, stream>>>(x, xb);
  transpose_kernel<<<dim3(64, 64), 256, 0, stream>>>(wq, wqkvT, 2048, 2048);
  transpose_kernel<<<dim3(16, 64), 256, 0, stream>>>(wk, wqkvT + (size_t)2048 * 2048, 2048, 512);
  transpose_kernel<<<dim3(16, 64), 256, 0, stream>>>(wv, wqkvT + (size_t)2560 * 2048, 2048, 512);
  transpose_kernel<<<dim3(64, 64), 256, 0, stream>>>(wo, woT, 2048, 2048);
  rope_tables_kernel<<<512, 256, 0, stream>>>(cosT, sinT);
  gemm_bt_kernel<0><<<dim3(24, 32), 256, 0, stream>>>(xb, wqkvT, (void*)QKV, 4096, 3072, 2048);
  rope_kernel<<<20480, 256, 0, stream>>>(QKV, cosT, sinT);
  v_transpose_kernel<<<dim3(32, 4, 8), 256, 0, stream>>>(QKV, Vt);
  attn_kernel<<<dim3(32, 32), 256, 0, stream>>>(QKV, Vt, AO);
  gemm_bt_kernel<1><<<dim3(16, 32), 256, 0, stream>>>(AO, woT, (void*)out, 4096, 2048, 2048);
}

// Round 3
// 283.720 us; speedup vs baseline: 1.4544x; 1.2251x over previous
//
#include <hip/hip_runtime.h>
#include <cstdint>

typedef unsigned short u16;
typedef __attribute__((ext_vector_type(8))) short bf16x8;
typedef __attribute__((ext_vector_type(4))) float f32x4;

static __device__ __forceinline__ float b2f(u16 u) {
  union { unsigned int i; float f; } v; v.i = ((unsigned int)u) << 16; return v.f;
}
static __device__ __forceinline__ u16 f2b(float f) {
  union { float f; unsigned int i; } v; v.f = f;
  unsigned int r = (v.i + 0x7FFFu + ((v.i >> 16) & 1u)) >> 16;
  return (u16)r;
}
static __device__ __forceinline__ void load_lds16(const void* g, void* l) {
  __builtin_amdgcn_global_load_lds((const __attribute__((address_space(1))) void*)g,
                                   (__attribute__((address_space(3))) void*)l, 16, 0, 0);
}

// ---------------- pack x (fp32 -> bf16), 4 elems/thread ----------------
__global__ void pack_x_kernel(const float* __restrict__ x, u16* __restrict__ xb) {
  int idx = blockIdx.x * 256 + threadIdx.x;
  float4 v = ((const float4*)x)[idx];
  unsigned long long pk = (unsigned long long)f2b(v.x)
                        | ((unsigned long long)f2b(v.y) << 16)
                        | ((unsigned long long)f2b(v.z) << 32)
                        | ((unsigned long long)f2b(v.w) << 48);
  ((unsigned long long*)xb)[idx] = pk;
}

// ---------------- transpose fp32 [R][C] -> bf16 [C][R] ----------------
__global__ void transpose_kernel(const float* __restrict__ src, u16* __restrict__ dst,
                                 int R, int C) {
  __shared__ float tile[32][33];
  int tx = threadIdx.x & 31, ty = threadIdx.x >> 5;
  int c0 = blockIdx.x * 32, r0 = blockIdx.y * 32;
#pragma unroll
  for (int i = 0; i < 4; ++i)
    tile[ty + i * 8][tx] = src[(size_t)(r0 + ty + i * 8) * C + c0 + tx];
  __syncthreads();
#pragma unroll
  for (int i = 0; i < 4; ++i)
    dst[(size_t)(c0 + ty + i * 8) * R + r0 + tx] = f2b(tile[tx][ty + i * 8]);
}

// ---------------- V transpose: QKV V-cols -> Vt [b*4+kv][128 d][2048 t] ----------------
__global__ void v_transpose_kernel(const u16* __restrict__ QKV, u16* __restrict__ Vt) {
  __shared__ __align__(16) u16 tile[32][80];
  const int bkv = blockIdx.z;            // 0..7
  const int b = bkv >> 2, kv = bkv & 3;
  const int d0 = blockIdx.y * 32;        // 0..96
  const int t0 = blockIdx.x * 64;        // 0..1984
  const int tid = threadIdx.x;
  const int tr = tid >> 2, dc = tid & 3;
  bf16x8 vv = *(const bf16x8*)(QKV + (size_t)(b * 2048 + t0 + tr) * 3072 + 2560 + kv * 128 + d0 + dc * 8);
#pragma unroll
  for (int e = 0; e < 8; ++e) tile[dc * 8 + e][tr] = (u16)vv[e];
  __syncthreads();
  const int d = tid >> 3, tc = tid & 7;
  *(bf16x8*)(Vt + (size_t)(bkv * 128 + d0 + d) * 2048 + t0 + tc * 8) =
      *(const bf16x8*)&tile[d][tc * 8];
}

// ---------------- RoPE tables: [T][64] cos/sin ----------------
__global__ void rope_tables_kernel(float* __restrict__ cosT, float* __restrict__ sinT) {
  int idx = blockIdx.x * 256 + threadIdx.x;  // T*64
  int t = idx >> 6, i = idx & 63;
  float inv = powf(10000.0f, -(float)i * (1.0f / 64.0f));
  float a = (float)t * inv;
  cosT[idx] = cosf(a);
  sinT[idx] = sinf(a);
}

// ---------------- GEMM: C[M][N] = A[M][K] * BT[N][K]^T  (bf16 in, OUTF=0 bf16 / 1 fp32 out)
template <int OUTF>
__global__ __launch_bounds__(256) void gemm_bt_kernel(const u16* __restrict__ A,
                                                      const u16* __restrict__ BT,
                                                      void* __restrict__ Cv,
                                                      int M, int N, int K) {
  __shared__ __align__(16) u16 lA[128 * 64];
  __shared__ __align__(16) u16 lB[128 * 64];
  const int tid = threadIdx.x;
  const int wave = tid >> 6, lane = tid & 63;
  const int wr = wave >> 1, wc = wave & 1;
  const int row0 = blockIdx.y * 128, col0 = blockIdx.x * 128;
  f32x4 acc[4][4];
#pragma unroll
  for (int m = 0; m < 4; ++m)
#pragma unroll
    for (int n = 0; n < 4; ++n) acc[m][n] = (f32x4){0.f, 0.f, 0.f, 0.f};
  const int rb = wave * 32;
  const int lrow = lane >> 3, lk = (lane & 7) * 8;
  for (int k0 = 0; k0 < K; k0 += 64) {
    __syncthreads();
    const u16* sA = A + (size_t)(row0 + rb + lrow) * K + k0 + lk;
    const u16* sB = BT + (size_t)(col0 + rb + lrow) * K + k0 + lk;
#pragma unroll
    for (int i = 0; i < 4; ++i) {
      load_lds16(sA + (size_t)i * 8 * K, &lA[(rb + i * 8) * 64]);
      load_lds16(sB + (size_t)i * 8 * K, &lB[(rb + i * 8) * 64]);
    }
    __syncthreads();
#pragma unroll
    for (int ks = 0; ks < 2; ++ks) {
      bf16x8 af[4], bfr[4];
#pragma unroll
      for (int m = 0; m < 4; ++m)
        af[m] = *(const bf16x8*)&lA[(wr * 64 + m * 16 + (lane & 15)) * 64 + ks * 32 + (lane >> 4) * 8];
#pragma unroll
      for (int n = 0; n < 4; ++n)
        bfr[n] = *(const bf16x8*)&lB[(wc * 64 + n * 16 + (lane & 15)) * 64 + ks * 32 + (lane >> 4) * 8];
#pragma unroll
      for (int m = 0; m < 4; ++m)
#pragma unroll
        for (int n = 0; n < 4; ++n)
          acc[m][n] = __builtin_amdgcn_mfma_f32_16x16x32_bf16(af[m], bfr[n], acc[m][n], 0, 0, 0);
    }
  }
  const int rbase = row0 + wr * 64 + ((lane >> 4) << 2);
  const int cbase = col0 + wc * 64 + (lane & 15);
#pragma unroll
  for (int m = 0; m < 4; ++m)
#pragma unroll
    for (int n = 0; n < 4; ++n)
#pragma unroll
      for (int j = 0; j < 4; ++j) {
        size_t off = (size_t)(rbase + m * 16 + j) * N + cbase + n * 16;
        if (OUTF == 0) ((u16*)Cv)[off] = f2b(acc[m][n][j]);
        else           ((float*)Cv)[off] = acc[m][n][j];
      }
}

// ---------------- RoPE in-place on Q,K columns of QKV [4096][3072] ----------------
__global__ void rope_kernel(u16* __restrict__ QKV, const float* __restrict__ cosT,
                            const float* __restrict__ sinT) {
  int idx = blockIdx.x * 256 + threadIdx.x;  // 4096*1280
  int row = idx / 1280;
  int rem = idx - row * 1280;
  int t = row & 2047;
  int i = rem & 63;
  int col;
  if (rem < 1024) col = (rem >> 6) * 128 + 2 * i;
  else { int r2 = rem - 1024; col = 2048 + (r2 >> 6) * 128 + 2 * i; }
  float c = cosT[t * 64 + i], s = sinT[t * 64 + i];
  size_t o = (size_t)row * 3072 + col;
  float x1 = b2f(QKV[o]), x2 = b2f(QKV[o + 1]);
  QKV[o]     = f2b(x1 * c - x2 * s);
  QKV[o + 1] = f2b(x1 * s + x2 * c);
}

// ---------------- fused SWA+meta GQA attention, 8-wave QBLK=128 ----------------
// grid: 512 blocks 1-D. lid&7 -> (b,kv) group (XCD-pinned); slot>>2 -> q-tile,
// slot&3 -> head-in-group. K and V double-buffered in LDS, staged with
// global_load_lds (pre-swizzled source, linear dest, swizzled read — T2/m173).
// Counted vmcnt(4): next tile's 4 staging ops stay in flight across compute.
__global__ __launch_bounds__(512) void attn_kernel(const u16* __restrict__ QKV,
                                                   const u16* __restrict__ Vt,
                                                   u16* __restrict__ AO) {
  __shared__ __align__(16) u16 lK[2][64 * 128];   // [key][dh-slot swz]  16KB x2
  __shared__ __align__(16) u16 lV[2][128 * 64];   // [dh][key-slot swz]  16KB x2
  __shared__ __align__(16) u16 lP[8][16 * 72];    // per-wave P [q][key]
  const int tid = threadIdx.x, wave = tid >> 6, lane = tid & 63;
  const int lid = blockIdx.x;
  const int g = lid & 7;                 // (b,kv) -> XCD g
  const int b = g >> 2, kv = g & 3;
  const int slot = lid >> 3;             // 0..63
  const int h = kv * 4 + (slot & 3);
  const int qt = slot >> 2;              // 0..15
  const int q0 = qt * 128;
  const int qw = q0 + wave * 16;
  const size_t rowbase = (size_t)(b * 2048) * 3072;
  const u16* Qb = QKV + rowbase + h * 128;
  const u16* Kb = QKV + rowbase + 2048 + kv * 128;
  const u16* Vb = Vt + (size_t)g * 128 * 2048;

  // Q fragments (16 q-rows per wave), stay in registers
  bf16x8 qf[4];
  {
    const u16* qs = Qb + (size_t)(qw + (lane & 15)) * 3072 + (lane >> 4) * 8;
#pragma unroll
    for (int s = 0; s < 4; ++s) qf[s] = *(const bf16x8*)(qs + s * 32);
  }
  f32x4 oacc[8];
#pragma unroll
  for (int n = 0; n < 8; ++n) oacc[n] = (f32x4){0.f, 0.f, 0.f, 0.f};
  float m_run[4] = {-1e30f, -1e30f, -1e30f, -1e30f};
  float l_run[4] = {0.f, 0.f, 0.f, 0.f};

  const int last_kt = 2 * qt + 1;
  const int kt_lo = (q0 > 1023) ? ((q0 - 1023) >> 6) : 0;
  const int nt = (last_kt - kt_lo + 1) + (kt_lo > 0 ? 1 : 0);
  const int qrb = qw + ((lane >> 4) << 2);

  // staging lambdas: per wave 2 ops K (8 rows) + 2 ops V (16 rows)
  auto stageK = [&](int buf, int kb) {
#pragma unroll
    for (int p = 0; p < 2; ++p) {
      const int r = wave * 8 + p * 4 + (lane >> 4);          // key row 0..63
      const int sc_ = ((lane & 15) ^ ((p * 4 + (lane >> 4)) & 7)) * 8;
      load_lds16(Kb + (size_t)(kb + r) * 3072 + sc_,
                 &lK[buf][(wave * 8 + p * 4) * 128]);
    }
  };
  auto stageV = [&](int buf, int kb) {
#pragma unroll
    for (int p = 0; p < 2; ++p) {
      const int d = wave * 16 + p * 8 + (lane >> 3);         // dh row 0..127
      const int sc_ = ((lane & 7) ^ (lane >> 3)) * 8;
      load_lds16(Vb + (size_t)d * 2048 + kb + sc_,
                 &lV[buf][(wave * 16 + p * 8) * 64]);
    }
  };

  // prologue: tile 0 is kb=0 in both enumeration cases
  stageK(0, 0);
  stageV(0, 0);

  int cur = 0;
  for (int it = 0; it < nt; ++it) {
    const int kt = (kt_lo > 0) ? (it == 0 ? 0 : kt_lo + it - 1) : it;
    const int kb = kt * 64;
    const bool pf = (it + 1 < nt);
    if (pf) {
      const int kbn = ((kt_lo > 0) ? (kt_lo + it) : (it + 1)) * 64;
      stageK(cur ^ 1, kbn);
      stageV(cur ^ 1, kbn);
      asm volatile("s_waitcnt vmcnt(4)" ::: "memory");
    } else {
      asm volatile("s_waitcnt vmcnt(0)" ::: "memory");
    }
    __syncthreads();  // buf[cur] ready for all waves

    // S = Q K^T (16q x 64key per wave), K from swizzled LDS
    f32x4 sc[4];
    __builtin_amdgcn_s_setprio(1);
#pragma unroll
    for (int ct = 0; ct < 4; ++ct) {
      f32x4 s = (f32x4){0.f, 0.f, 0.f, 0.f};
      const int kr = ct * 16 + (lane & 15);
#pragma unroll
      for (int ss = 0; ss < 4; ++ss) {
        const int ksl = (ss * 4 + (lane >> 4)) ^ (lane & 7);
        bf16x8 kf = *(const bf16x8*)&lK[cur][kr * 128 + ksl * 8];
        s = __builtin_amdgcn_mfma_f32_16x16x32_bf16(qf[ss], kf, s, 0, 0, 0);
      }
      sc[ct] = s;
    }
    __builtin_amdgcn_s_setprio(0);

    const float scale = 0.08838834764831845f;  // 1/sqrt(128)
#pragma unroll
    for (int ct = 0; ct < 4; ++ct) {
      const int key = kb + ct * 16 + (lane & 15);
#pragma unroll
      for (int j = 0; j < 4; ++j) {
        const int q = qrb + j;
        float sv = sc[ct][j] * scale;
        bool ok = (key < 16) || (key <= q && (q - key) < 1024);
        sc[ct][j] = ok ? sv : -1e30f;
      }
    }
    float mt[4], rs[4], alpha[4];
#pragma unroll
    for (int j = 0; j < 4; ++j)
      mt[j] = fmaxf(fmaxf(sc[0][j], sc[1][j]), fmaxf(sc[2][j], sc[3][j]));
#pragma unroll
    for (int off = 1; off < 16; off <<= 1)
#pragma unroll
      for (int j = 0; j < 4; ++j)
        mt[j] = fmaxf(mt[j], __shfl_xor(mt[j], off, 16));
#pragma unroll
    for (int j = 0; j < 4; ++j) {
      float mn = fmaxf(m_run[j], mt[j]);
      alpha[j] = __expf(m_run[j] - mn);
      m_run[j] = mn;
    }
#pragma unroll
    for (int ct = 0; ct < 4; ++ct)
#pragma unroll
      for (int j = 0; j < 4; ++j)
        sc[ct][j] = __expf(sc[ct][j] - m_run[j]);
#pragma unroll
    for (int j = 0; j < 4; ++j)
      rs[j] = (sc[0][j] + sc[1][j]) + (sc[2][j] + sc[3][j]);
#pragma unroll
    for (int off = 1; off < 16; off <<= 1)
#pragma unroll
      for (int j = 0; j < 4; ++j)
        rs[j] += __shfl_xor(rs[j], off, 16);
#pragma unroll
    for (int j = 0; j < 4; ++j)
      l_run[j] = l_run[j] * alpha[j] + rs[j];
#pragma unroll
    for (int n = 0; n < 8; ++n)
#pragma unroll
      for (int j = 0; j < 4; ++j)
        oacc[n][j] *= alpha[j];

    // write P tile (per-wave region; intra-wave ordering via lgkmcnt)
    u16* Pw = &lP[wave][0];
#pragma unroll
    for (int ct = 0; ct < 4; ++ct)
#pragma unroll
      for (int j = 0; j < 4; ++j)
        Pw[(((lane >> 4) << 2) + j) * 72 + ct * 16 + (lane & 15)] = f2b(sc[ct][j]);

    // O += P V  (V B-frags from swizzled LDS: slot = chunk ^ (row&7))
    __builtin_amdgcn_s_setprio(1);
#pragma unroll
    for (int kss = 0; kss < 2; ++kss) {
      bf16x8 pa = *(const bf16x8*)&Pw[(lane & 15) * 72 + kss * 32 + (lane >> 4) * 8];
#pragma unroll
      for (int n = 0; n < 8; ++n) {
        const int vrow = n * 16 + (lane & 15);
        const int vsl = (kss * 4 + (lane >> 4)) ^ (lane & 7);
        bf16x8 vf = *(const bf16x8*)&lV[cur][vrow * 64 + vsl * 8];
        oacc[n] = __builtin_amdgcn_mfma_f32_16x16x32_bf16(pa, vf, oacc[n], 0, 0, 0);
      }
    }
    __builtin_amdgcn_s_setprio(0);
    __syncthreads();  // all waves done reading buf[cur] before it is restaged
    cur ^= 1;
  }
#pragma unroll
  for (int j = 0; j < 4; ++j) {
    const float inv = 1.0f / l_run[j];
    const size_t rowo = (size_t)(b * 2048 + qrb + j) * 2048 + h * 128;
#pragma unroll
    for (int n = 0; n < 8; ++n)
      AO[rowo + n * 16 + (lane & 15)] = f2b(oacc[n][j] * inv);
  }
}

extern "C" void kernel_launch(void* const* d_in, const int* in_sizes, int n_in,
                              void* d_out, int out_size, void* d_ws, size_t ws_size,
                              hipStream_t stream) {
  (void)in_sizes; (void)n_in; (void)out_size; (void)ws_size;
  const float* x  = (const float*)d_in[0];
  const float* wq = (const float*)d_in[1];
  const float* wk = (const float*)d_in[2];
  const float* wv = (const float*)d_in[3];
  const float* wo = (const float*)d_in[4];
  float* out = (float*)d_out;

  // workspace carve (~68 MB)
  u16* xb    = (u16*)d_ws;                         // [4096][2048]
  u16* wqkvT = xb    + (size_t)4096 * 2048;        // [3072][2048]
  u16* woT   = wqkvT + (size_t)3072 * 2048;        // [2048][2048]
  u16* QKV   = woT   + (size_t)2048 * 2048;        // [4096][3072]
  u16* Vt    = QKV   + (size_t)4096 * 3072;        // [8][128][2048]
  float* cosT = (float*)(Vt + (size_t)8 * 128 * 2048);  // [2048][64]
  float* sinT = cosT + 2048 * 64;
  u16* AO = xb;  // alias: xb dead after QKV GEMM

  pack_x_kernel<<<8192, 256, 0, stream>>>(x, xb);
  transpose_kernel<<<dim3(64, 64), 256, 0, stream>>>(wq, wqkvT, 2048, 2048);
  transpose_kernel<<<dim3(16, 64), 256, 0, stream>>>(wk, wqkvT + (size_t)2048 * 2048, 2048, 512);
  transpose_kernel<<<dim3(16, 64), 256, 0, stream>>>(wv, wqkvT + (size_t)2560 * 2048, 2048, 512);
  transpose_kernel<<<dim3(64, 64), 256, 0, stream>>>(wo, woT, 2048, 2048);
  rope_tables_kernel<<<512, 256, 0, stream>>>(cosT, sinT);
  gemm_bt_kernel<0><<<dim3(24, 32), 256, 0, stream>>>(xb, wqkvT, (void*)QKV, 4096, 3072, 2048);
  rope_kernel<<<20480, 256, 0, stream>>>(QKV, cosT, sinT);
  v_transpose_kernel<<<dim3(32, 4, 8), 256, 0, stream>>>(QKV, Vt);
  attn_kernel<<<512, 512, 0, stream>>>(QKV, Vt, AO);
  gemm_bt_kernel<1><<<dim3(16, 32), 256, 0, stream>>>(AO, woT, (void*)out, 4096, 2048, 2048);
}

// Round 4
// 269.264 us; speedup vs baseline: 1.5325x; 1.0537x over previous
//
#include <hip/hip_runtime.h>
#include <cstdint>

typedef unsigned short u16;
typedef __attribute__((ext_vector_type(8))) short bf16x8;
typedef __attribute__((ext_vector_type(4))) float f32x4;

static __device__ __forceinline__ float b2f(u16 u) {
  union { unsigned int i; float f; } v; v.i = ((unsigned int)u) << 16; return v.f;
}
static __device__ __forceinline__ u16 f2b(float f) {
  union { float f; unsigned int i; } v; v.f = f;
  unsigned int r = (v.i + 0x7FFFu + ((v.i >> 16) & 1u)) >> 16;
  return (u16)r;
}
static __device__ __forceinline__ void load_lds16(const void* g, void* l) {
  __builtin_amdgcn_global_load_lds((const __attribute__((address_space(1))) void*)g,
                                   (__attribute__((address_space(3))) void*)l, 16, 0, 0);
}

// ---------------- pack x (fp32 -> bf16), 4 elems/thread ----------------
__global__ void pack_x_kernel(const float* __restrict__ x, u16* __restrict__ xb) {
  int idx = blockIdx.x * 256 + threadIdx.x;
  float4 v = ((const float4*)x)[idx];
  unsigned long long pk = (unsigned long long)f2b(v.x)
                        | ((unsigned long long)f2b(v.y) << 16)
                        | ((unsigned long long)f2b(v.z) << 32)
                        | ((unsigned long long)f2b(v.w) << 48);
  ((unsigned long long*)xb)[idx] = pk;
}

// ---------------- transpose fp32 [R][C] -> bf16 [C][R] ----------------
__global__ void transpose_kernel(const float* __restrict__ src, u16* __restrict__ dst,
                                 int R, int C) {
  __shared__ float tile[32][33];
  int tx = threadIdx.x & 31, ty = threadIdx.x >> 5;
  int c0 = blockIdx.x * 32, r0 = blockIdx.y * 32;
#pragma unroll
  for (int i = 0; i < 4; ++i)
    tile[ty + i * 8][tx] = src[(size_t)(r0 + ty + i * 8) * C + c0 + tx];
  __syncthreads();
#pragma unroll
  for (int i = 0; i < 4; ++i)
    dst[(size_t)(c0 + ty + i * 8) * R + r0 + tx] = f2b(tile[tx][ty + i * 8]);
}

// ---------------- V transpose: QKV V-cols -> Vt [b*4+kv][128 d][2048 t] ----------------
__global__ void v_transpose_kernel(const u16* __restrict__ QKV, u16* __restrict__ Vt) {
  __shared__ __align__(16) u16 tile[32][80];
  const int bkv = blockIdx.z;            // 0..7
  const int b = bkv >> 2, kv = bkv & 3;
  const int d0 = blockIdx.y * 32;        // 0..96
  const int t0 = blockIdx.x * 64;        // 0..1984
  const int tid = threadIdx.x;
  const int tr = tid >> 2, dc = tid & 3;
  bf16x8 vv = *(const bf16x8*)(QKV + (size_t)(b * 2048 + t0 + tr) * 3072 + 2560 + kv * 128 + d0 + dc * 8);
#pragma unroll
  for (int e = 0; e < 8; ++e) tile[dc * 8 + e][tr] = (u16)vv[e];
  __syncthreads();
  const int d = tid >> 3, tc = tid & 7;
  *(bf16x8*)(Vt + (size_t)(bkv * 128 + d0 + d) * 2048 + t0 + tc * 8) =
      *(const bf16x8*)&tile[d][tc * 8];
}

// ---------------- RoPE tables: [T][64] cos/sin ----------------
__global__ void rope_tables_kernel(float* __restrict__ cosT, float* __restrict__ sinT) {
  int idx = blockIdx.x * 256 + threadIdx.x;  // T*64
  int t = idx >> 6, i = idx & 63;
  float inv = powf(10000.0f, -(float)i * (1.0f / 64.0f));
  float a = (float)t * inv;
  cosT[idx] = cosf(a);
  sinT[idx] = sinf(a);
}

// ---------------- GEMM: C[M][N] = A[M][K] * BT[N][K]^T  (bf16 in, OUTF=0 bf16 / 1 fp32 out)
template <int OUTF>
__global__ __launch_bounds__(256) void gemm_bt_kernel(const u16* __restrict__ A,
                                                      const u16* __restrict__ BT,
                                                      void* __restrict__ Cv,
                                                      int M, int N, int K) {
  __shared__ __align__(16) u16 lA[128 * 64];
  __shared__ __align__(16) u16 lB[128 * 64];
  const int tid = threadIdx.x;
  const int wave = tid >> 6, lane = tid & 63;
  const int wr = wave >> 1, wc = wave & 1;
  const int row0 = blockIdx.y * 128, col0 = blockIdx.x * 128;
  f32x4 acc[4][4];
#pragma unroll
  for (int m = 0; m < 4; ++m)
#pragma unroll
    for (int n = 0; n < 4; ++n) acc[m][n] = (f32x4){0.f, 0.f, 0.f, 0.f};
  const int rb = wave * 32;
  const int lrow = lane >> 3, lk = (lane & 7) * 8;
  for (int k0 = 0; k0 < K; k0 += 64) {
    __syncthreads();
    const u16* sA = A + (size_t)(row0 + rb + lrow) * K + k0 + lk;
    const u16* sB = BT + (size_t)(col0 + rb + lrow) * K + k0 + lk;
#pragma unroll
    for (int i = 0; i < 4; ++i) {
      load_lds16(sA + (size_t)i * 8 * K, &lA[(rb + i * 8) * 64]);
      load_lds16(sB + (size_t)i * 8 * K, &lB[(rb + i * 8) * 64]);
    }
    __syncthreads();
#pragma unroll
    for (int ks = 0; ks < 2; ++ks) {
      bf16x8 af[4], bfr[4];
#pragma unroll
      for (int m = 0; m < 4; ++m)
        af[m] = *(const bf16x8*)&lA[(wr * 64 + m * 16 + (lane & 15)) * 64 + ks * 32 + (lane >> 4) * 8];
#pragma unroll
      for (int n = 0; n < 4; ++n)
        bfr[n] = *(const bf16x8*)&lB[(wc * 64 + n * 16 + (lane & 15)) * 64 + ks * 32 + (lane >> 4) * 8];
#pragma unroll
      for (int m = 0; m < 4; ++m)
#pragma unroll
        for (int n = 0; n < 4; ++n)
          acc[m][n] = __builtin_amdgcn_mfma_f32_16x16x32_bf16(af[m], bfr[n], acc[m][n], 0, 0, 0);
    }
  }
  const int rbase = row0 + wr * 64 + ((lane >> 4) << 2);
  const int cbase = col0 + wc * 64 + (lane & 15);
#pragma unroll
  for (int m = 0; m < 4; ++m)
#pragma unroll
    for (int n = 0; n < 4; ++n)
#pragma unroll
      for (int j = 0; j < 4; ++j) {
        size_t off = (size_t)(rbase + m * 16 + j) * N + cbase + n * 16;
        if (OUTF == 0) ((u16*)Cv)[off] = f2b(acc[m][n][j]);
        else           ((float*)Cv)[off] = acc[m][n][j];
      }
}

// ---------------- RoPE in-place on Q,K columns of QKV [4096][3072] ----------------
__global__ void rope_kernel(u16* __restrict__ QKV, const float* __restrict__ cosT,
                            const float* __restrict__ sinT) {
  int idx = blockIdx.x * 256 + threadIdx.x;  // 4096*1280
  int row = idx / 1280;
  int rem = idx - row * 1280;
  int t = row & 2047;
  int i = rem & 63;
  int col;
  if (rem < 1024) col = (rem >> 6) * 128 + 2 * i;
  else { int r2 = rem - 1024; col = 2048 + (r2 >> 6) * 128 + 2 * i; }
  float c = cosT[t * 64 + i], s = sinT[t * 64 + i];
  size_t o = (size_t)row * 3072 + col;
  float x1 = b2f(QKV[o]), x2 = b2f(QKV[o + 1]);
  QKV[o]     = f2b(x1 * c - x2 * s);
  QKV[o + 1] = f2b(x1 * s + x2 * c);
}

// ---------------- fused SWA+meta GQA attention, 4-wave QBLK=64, swapped QK^T ----
// grid 1024: lid&7 -> (b,kv) (XCD-pinned), (lid>>3)&3 -> head-in-group,
// lid>>5 -> q-tile (64 rows). K,V double-buffered LDS (global_load_lds,
// pre-swizzled source / swizzled read). LDS 74.5KB -> 2 independent blocks/CU.
// QK^T computed SWAPPED: mfma(K,Q) => D[col=q][row=key]; each lane owns one q,
// 16 keys in-register -> softmax reduce = in-reg + 2 shfl_xor; m/l scalar.
__global__ __launch_bounds__(256) void attn_kernel(const u16* __restrict__ QKV,
                                                   const u16* __restrict__ Vt,
                                                   u16* __restrict__ AO) {
  __shared__ __align__(16) u16 lK[2][64 * 128];   // [key][dh swz]  16KB x2
  __shared__ __align__(16) u16 lV[2][128 * 64];   // [dh][key swz]  16KB x2
  __shared__ __align__(16) u16 lP[4][16 * 70];    // per-wave P [q][key], stride 70
  const int tid = threadIdx.x, wave = tid >> 6, lane = tid & 63;
  const int lid = blockIdx.x;
  const int g = lid & 7;                 // (b,kv)
  const int b = g >> 2, kv = g & 3;
  const int h = kv * 4 + ((lid >> 3) & 3);
  const int qt = lid >> 5;               // 0..31
  const int q0 = qt * 64;
  const int qw = q0 + wave * 16;
  const size_t rowbase = (size_t)(b * 2048) * 3072;
  const u16* Qb = QKV + rowbase + h * 128;
  const u16* Kb = QKV + rowbase + 2048 + kv * 128;
  const u16* Vb = Vt + (size_t)g * 128 * 2048;

  // Q fragments as MFMA B-operand: col=lane&15 -> q row, k-slice (lane>>4)*8
  bf16x8 qf[4];
  {
    const u16* qs = Qb + (size_t)(qw + (lane & 15)) * 3072 + (lane >> 4) * 8;
#pragma unroll
    for (int s = 0; s < 4; ++s) qf[s] = *(const bf16x8*)(qs + s * 32);
  }
  f32x4 oacc[8];
#pragma unroll
  for (int n = 0; n < 8; ++n) oacc[n] = (f32x4){0.f, 0.f, 0.f, 0.f};
  float m_run = -1e30f, l_run = 0.f;     // per-lane scalars (lane's q = qw+(lane&15))

  const int kt_lo = (q0 > 1023) ? ((q0 - 1023) >> 6) : 0;
  const int nt = (qt - kt_lo + 1) + (kt_lo > 0 ? 1 : 0);

  // staging: per wave 4 K ops (16 rows) + 4 V ops (32 rows)
  auto stageK = [&](int buf, int kb) {
#pragma unroll
    for (int p = 0; p < 4; ++p) {
      const int rr = p * 4 + (lane >> 4);                    // row within wave's 16
      const int sc_ = ((lane & 15) ^ (rr & 7)) * 8;
      load_lds16(Kb + (size_t)(kb + wave * 16 + rr) * 3072 + sc_,
                 &lK[buf][(wave * 16 + p * 4) * 128]);
    }
  };
  auto stageV = [&](int buf, int kb) {
#pragma unroll
    for (int p = 0; p < 4; ++p) {
      const int d = wave * 32 + p * 8 + (lane >> 3);         // dh row, d&7 = lane>>3
      const int sc_ = ((lane & 7) ^ (lane >> 3)) * 8;
      load_lds16(Vb + (size_t)d * 2048 + kb + sc_,
                 &lV[buf][(wave * 32 + p * 8) * 64]);
    }
  };

  stageK(0, 0);
  stageV(0, 0);

  const int qmine = qw + (lane & 15);    // this lane's q row
  int cur = 0;
  for (int it = 0; it < nt; ++it) {
    const int kt = (kt_lo > 0) ? (it == 0 ? 0 : kt_lo + it - 1) : it;
    const int kb = kt * 64;
    if (it + 1 < nt) {
      const int kbn = ((kt_lo > 0) ? (kt_lo + it) : (it + 1)) * 64;
      stageK(cur ^ 1, kbn);
      stageV(cur ^ 1, kbn);
      asm volatile("s_waitcnt vmcnt(8)" ::: "memory");
    } else {
      asm volatile("s_waitcnt vmcnt(0)" ::: "memory");
    }
    __syncthreads();  // buf[cur] ready for all waves

    // S^T = K Q^T: A=K (row=key), B=Q (col=q). D: col=lane&15=q,
    // row=(lane>>4)*4+j = key-within-16 (+ct*16).
    f32x4 sc[4];
    __builtin_amdgcn_s_setprio(1);
#pragma unroll
    for (int ct = 0; ct < 4; ++ct) {
      f32x4 s = (f32x4){0.f, 0.f, 0.f, 0.f};
      const int kr = ct * 16 + (lane & 15);                  // kr&7 == lane&7
#pragma unroll
      for (int ss = 0; ss < 4; ++ss) {
        const int ksl = (ss * 4 + (lane >> 4)) ^ (lane & 7);
        bf16x8 kf = *(const bf16x8*)&lK[cur][kr * 128 + ksl * 8];
        s = __builtin_amdgcn_mfma_f32_16x16x32_bf16(kf, qf[ss], s, 0, 0, 0);
      }
      sc[ct] = s;
    }
    __builtin_amdgcn_s_setprio(0);

    const float scale = 0.08838834764831845f;  // 1/sqrt(128)
    // mask + scale; this lane's 16 keys: kb + ct*16 + (lane>>4)*4 + j
#pragma unroll
    for (int ct = 0; ct < 4; ++ct) {
      const int kbase = kb + ct * 16 + ((lane >> 4) << 2);
#pragma unroll
      for (int j = 0; j < 4; ++j) {
        const int key = kbase + j;
        float sv = sc[ct][j] * scale;
        bool ok = (key < 16) || (key <= qmine && (qmine - key) < 1024);
        sc[ct][j] = ok ? sv : -1e30f;
      }
    }
    // tile max: 16 in-register + 2 shfl_xor across hi-groups (lanes +-16,32)
    float mt = sc[0][0];
#pragma unroll
    for (int ct = 0; ct < 4; ++ct)
#pragma unroll
      for (int j = 0; j < 4; ++j) mt = fmaxf(mt, sc[ct][j]);
    mt = fmaxf(mt, __shfl_xor(mt, 16));
    mt = fmaxf(mt, __shfl_xor(mt, 32));
    const float mn = fmaxf(m_run, mt);
    const float alpha = __expf(m_run - mn);
    m_run = mn;
    float rs = 0.f;
#pragma unroll
    for (int ct = 0; ct < 4; ++ct)
#pragma unroll
      for (int j = 0; j < 4; ++j) {
        sc[ct][j] = __expf(sc[ct][j] - mn);
        rs += sc[ct][j];
      }
    rs += __shfl_xor(rs, 16);
    rs += __shfl_xor(rs, 32);
    l_run = l_run * alpha + rs;

    // broadcast alpha to the q-rows this lane accumulates in oacc
    float abc[4];
#pragma unroll
    for (int j = 0; j < 4; ++j)
      abc[j] = __shfl(alpha, ((lane >> 4) << 2) + j, 16);
#pragma unroll
    for (int n = 0; n < 8; ++n)
#pragma unroll
      for (int j = 0; j < 4; ++j)
        oacc[n][j] *= abc[j];

    // write P tile: P[q=lane&15][key = ct*16 + (lane>>4)*4 + j], stride 70
    u16* Pw = &lP[wave][0];
#pragma unroll
    for (int ct = 0; ct < 4; ++ct)
#pragma unroll
      for (int j = 0; j < 4; ++j)
        Pw[(lane & 15) * 70 + ct * 16 + ((lane >> 4) << 2) + j] = f2b(sc[ct][j]);

    // O += P V  (pa: A-frag row=lane&15=q, k-slice (lane>>4)*8)
    __builtin_amdgcn_s_setprio(1);
#pragma unroll
    for (int kss = 0; kss < 2; ++kss) {
      bf16x8 pa = *(const bf16x8*)&Pw[(lane & 15) * 70 + kss * 32 + (lane >> 4) * 8];
#pragma unroll
      for (int n = 0; n < 8; ++n) {
        const int vrow = n * 16 + (lane & 15);               // vrow&7 == lane&7
        const int vsl = (kss * 4 + (lane >> 4)) ^ (lane & 7);
        bf16x8 vf = *(const bf16x8*)&lV[cur][vrow * 64 + vsl * 8];
        oacc[n] = __builtin_amdgcn_mfma_f32_16x16x32_bf16(pa, vf, oacc[n], 0, 0, 0);
      }
    }
    __builtin_amdgcn_s_setprio(0);
    __syncthreads();  // all waves done reading buf[cur] before restage
    cur ^= 1;
  }
  // epilogue: broadcast 1/l to oacc's q-rows
  const float linv = 1.0f / l_run;
  const int qrb = qw + ((lane >> 4) << 2);
#pragma unroll
  for (int j = 0; j < 4; ++j) {
    const float inv = __shfl(linv, ((lane >> 4) << 2) + j, 16);
    const size_t rowo = (size_t)(b * 2048 + qrb + j) * 2048 + h * 128;
#pragma unroll
    for (int n = 0; n < 8; ++n)
      AO[rowo + n * 16 + (lane & 15)] = f2b(oacc[n][j] * inv);
  }
}

extern "C" void kernel_launch(void* const* d_in, const int* in_sizes, int n_in,
                              void* d_out, int out_size, void* d_ws, size_t ws_size,
                              hipStream_t stream) {
  (void)in_sizes; (void)n_in; (void)out_size; (void)ws_size;
  const float* x  = (const float*)d_in[0];
  const float* wq = (const float*)d_in[1];
  const float* wk = (const float*)d_in[2];
  const float* wv = (const float*)d_in[3];
  const float* wo = (const float*)d_in[4];
  float* out = (float*)d_out;

  // workspace carve (~68 MB)
  u16* xb    = (u16*)d_ws;                         // [4096][2048]
  u16* wqkvT = xb    + (size_t)4096 * 2048;        // [3072][2048]
  u16* woT   = wqkvT + (size_t)3072 * 2048;        // [2048][2048]
  u16* QKV   = woT   + (size_t)2048 * 2048;        // [4096][3072]
  u16* Vt    = QKV   + (size_t)4096 * 3072;        // [8][128][2048]
  float* cosT = (float*)(Vt + (size_t)8 * 128 * 2048);  // [2048][64]
  float* sinT = cosT + 2048 * 64;
  u16* AO = xb;  // alias: xb dead after QKV GEMM

  pack_x_kernel<<<8192, 256, 0, stream>>>(x, xb);
  transpose_kernel<<<dim3(64, 64), 256, 0, stream>>>(wq, wqkvT, 2048, 2048);
  transpose_kernel<<<dim3(16, 64), 256, 0, stream>>>(wk, wqkvT + (size_t)2048 * 2048, 2048, 512);
  transpose_kernel<<<dim3(16, 64), 256, 0, stream>>>(wv, wqkvT + (size_t)2560 * 2048, 2048, 512);
  transpose_kernel<<<dim3(64, 64), 256, 0, stream>>>(wo, woT, 2048, 2048);
  rope_tables_kernel<<<512, 256, 0, stream>>>(cosT, sinT);
  gemm_bt_kernel<0><<<dim3(24, 32), 256, 0, stream>>>(xb, wqkvT, (void*)QKV, 4096, 3072, 2048);
  rope_kernel<<<20480, 256, 0, stream>>>(QKV, cosT, sinT);
  v_transpose_kernel<<<dim3(32, 4, 8), 256, 0, stream>>>(QKV, Vt);
  attn_kernel<<<1024, 256, 0, stream>>>(QKV, Vt, AO);
  gemm_bt_kernel<1><<<dim3(16, 32), 256, 0, stream>>>(AO, woT, (void*)out, 4096, 2048, 2048);
}

// Round 5
// 237.490 us; speedup vs baseline: 1.7376x; 1.1338x over previous
//
#include <hip/hip_runtime.h>
#include <cstdint>

typedef unsigned short u16;
typedef __attribute__((ext_vector_type(8))) short bf16x8;
typedef __attribute__((ext_vector_type(4))) float f32x4;

static __device__ __forceinline__ float b2f(u16 u) {
  union { unsigned int i; float f; } v; v.i = ((unsigned int)u) << 16; return v.f;
}
static __device__ __forceinline__ u16 f2b(float f) {
  union { float f; unsigned int i; } v; v.f = f;
  unsigned int r = (v.i + 0x7FFFu + ((v.i >> 16) & 1u)) >> 16;
  return (u16)r;
}
static __device__ __forceinline__ void load_lds16(const void* g, void* l) {
  __builtin_amdgcn_global_load_lds((const __attribute__((address_space(1))) void*)g,
                                   (__attribute__((address_space(3))) void*)l, 16, 0, 0);
}

// ---------------- pack x (fp32 -> bf16), 4 elems/thread ----------------
__global__ void pack_x_kernel(const float* __restrict__ x, u16* __restrict__ xb) {
  int idx = blockIdx.x * 256 + threadIdx.x;
  float4 v = ((const float4*)x)[idx];
  unsigned long long pk = (unsigned long long)f2b(v.x)
                        | ((unsigned long long)f2b(v.y) << 16)
                        | ((unsigned long long)f2b(v.z) << 32)
                        | ((unsigned long long)f2b(v.w) << 48);
  ((unsigned long long*)xb)[idx] = pk;
}

// ---------------- transpose fp32 [R][C] -> bf16 [C][R] ----------------
__global__ void transpose_kernel(const float* __restrict__ src, u16* __restrict__ dst,
                                 int R, int C) {
  __shared__ float tile[32][33];
  int tx = threadIdx.x & 31, ty = threadIdx.x >> 5;
  int c0 = blockIdx.x * 32, r0 = blockIdx.y * 32;
#pragma unroll
  for (int i = 0; i < 4; ++i)
    tile[ty + i * 8][tx] = src[(size_t)(r0 + ty + i * 8) * C + c0 + tx];
  __syncthreads();
#pragma unroll
  for (int i = 0; i < 4; ++i)
    dst[(size_t)(c0 + ty + i * 8) * R + r0 + tx] = f2b(tile[tx][ty + i * 8]);
}

// ---------------- V transpose: QKV V-cols -> Vt [b*4+kv][128 d][2048 t] ----------------
__global__ void v_transpose_kernel(const u16* __restrict__ QKV, u16* __restrict__ Vt) {
  __shared__ __align__(16) u16 tile[32][80];
  const int bkv = blockIdx.z;            // 0..7
  const int b = bkv >> 2, kv = bkv & 3;
  const int d0 = blockIdx.y * 32;        // 0..96
  const int t0 = blockIdx.x * 64;        // 0..1984
  const int tid = threadIdx.x;
  const int tr = tid >> 2, dc = tid & 3;
  bf16x8 vv = *(const bf16x8*)(QKV + (size_t)(b * 2048 + t0 + tr) * 3072 + 2560 + kv * 128 + d0 + dc * 8);
#pragma unroll
  for (int e = 0; e < 8; ++e) tile[dc * 8 + e][tr] = (u16)vv[e];
  __syncthreads();
  const int d = tid >> 3, tc = tid & 7;
  *(bf16x8*)(Vt + (size_t)(bkv * 128 + d0 + d) * 2048 + t0 + tc * 8) =
      *(const bf16x8*)&tile[d][tc * 8];
}

// ---------------- RoPE tables: [T][64] cos/sin ----------------
__global__ void rope_tables_kernel(float* __restrict__ cosT, float* __restrict__ sinT) {
  int idx = blockIdx.x * 256 + threadIdx.x;  // T*64
  int t = idx >> 6, i = idx & 63;
  float inv = powf(10000.0f, -(float)i * (1.0f / 64.0f));
  float a = (float)t * inv;
  cosT[idx] = cosf(a);
  sinT[idx] = sinf(a);
}

// ---------------- GEMM: C[M][N] = A[M][K] * BT[N][K]^T  (bf16 in, OUTF=0 bf16 / 1 fp32 out)
// Pipelined: depth-1 prefetch, counted vmcnt(8), raw barriers (no drain),
// chunk-XOR LDS swizzle (pre-swizzled global source / swizzled ds_read).
template <int OUTF>
__global__ __launch_bounds__(256) void gemm_bt_kernel(const u16* __restrict__ A,
                                                      const u16* __restrict__ BT,
                                                      void* __restrict__ Cv,
                                                      int M, int N, int K) {
  __shared__ __align__(16) u16 lA[2][128 * 64];
  __shared__ __align__(16) u16 lB[2][128 * 64];
  const int tid = threadIdx.x;
  const int wave = tid >> 6, lane = tid & 63;
  const int wr = wave >> 1, wc = wave & 1;
  const int row0 = blockIdx.y * 128, col0 = blockIdx.x * 128;
  f32x4 acc[4][4];
#pragma unroll
  for (int m = 0; m < 4; ++m)
#pragma unroll
    for (int n = 0; n < 4; ++n) acc[m][n] = (f32x4){0.f, 0.f, 0.f, 0.f};
  const int rb = wave * 32;
  const int lrow = lane >> 3;          // 0..7 (row within 8-row stage group)
  const int schk = ((lane & 7) ^ lrow) * 8;  // pre-swizzled source chunk
  const u16* pA = A + (size_t)(row0 + rb + lrow) * K + schk;
  const u16* pB = BT + (size_t)(col0 + rb + lrow) * K + schk;
  const int NT = K >> 6;

  // prologue: stage tile 0 into buf 0 (8 ops in flight)
#pragma unroll
  for (int i = 0; i < 4; ++i) {
    load_lds16(pA + (size_t)i * 8 * K, &lA[0][(rb + i * 8) * 64]);
    load_lds16(pB + (size_t)i * 8 * K, &lB[0][(rb + i * 8) * 64]);
  }

  for (int t = 0; t < NT; ++t) {
    const int cur = t & 1;
    if (t + 1 < NT) {
      const size_t k1 = (size_t)(t + 1) << 6;
#pragma unroll
      for (int i = 0; i < 4; ++i) {
        load_lds16(pA + k1 + (size_t)i * 8 * K, &lA[cur ^ 1][(rb + i * 8) * 64]);
        load_lds16(pB + k1 + (size_t)i * 8 * K, &lB[cur ^ 1][(rb + i * 8) * 64]);
      }
      asm volatile("s_waitcnt vmcnt(8)" ::: "memory");  // tile t landed; t+1 in flight
    } else {
      asm volatile("s_waitcnt vmcnt(0)" ::: "memory");
    }
    __builtin_amdgcn_s_barrier();            // buf[cur] ready for all waves (no drain)
    __builtin_amdgcn_sched_barrier(0);
    __builtin_amdgcn_s_setprio(1);
#pragma unroll
    for (int ks = 0; ks < 2; ++ks) {
      bf16x8 af[4], bfr[4];
      const int sl = ((ks * 4 + (lane >> 4)) ^ (lane & 7)) * 8;  // swizzled read slot
#pragma unroll
      for (int m = 0; m < 4; ++m)
        af[m] = *(const bf16x8*)&lA[cur][(wr * 64 + m * 16 + (lane & 15)) * 64 + sl];
#pragma unroll
      for (int n = 0; n < 4; ++n)
        bfr[n] = *(const bf16x8*)&lB[cur][(wc * 64 + n * 16 + (lane & 15)) * 64 + sl];
#pragma unroll
      for (int m = 0; m < 4; ++m)
#pragma unroll
        for (int n = 0; n < 4; ++n)
          acc[m][n] = __builtin_amdgcn_mfma_f32_16x16x32_bf16(af[m], bfr[n], acc[m][n], 0, 0, 0);
    }
    __builtin_amdgcn_s_setprio(0);
    __builtin_amdgcn_sched_barrier(0);
    __builtin_amdgcn_s_barrier();            // all waves done reading buf[cur]
  }
  const int rbase = row0 + wr * 64 + ((lane >> 4) << 2);
  const int cbase = col0 + wc * 64 + (lane & 15);
#pragma unroll
  for (int m = 0; m < 4; ++m)
#pragma unroll
    for (int n = 0; n < 4; ++n)
#pragma unroll
      for (int j = 0; j < 4; ++j) {
        size_t off = (size_t)(rbase + m * 16 + j) * N + cbase + n * 16;
        if (OUTF == 0) ((u16*)Cv)[off] = f2b(acc[m][n][j]);
        else           ((float*)Cv)[off] = acc[m][n][j];
      }
}

// ---------------- RoPE in-place on Q,K columns of QKV [4096][3072] ----------------
__global__ void rope_kernel(u16* __restrict__ QKV, const float* __restrict__ cosT,
                            const float* __restrict__ sinT) {
  int idx = blockIdx.x * 256 + threadIdx.x;  // 4096*1280
  int row = idx / 1280;
  int rem = idx - row * 1280;
  int t = row & 2047;
  int i = rem & 63;
  int col;
  if (rem < 1024) col = (rem >> 6) * 128 + 2 * i;
  else { int r2 = rem - 1024; col = 2048 + (r2 >> 6) * 128 + 2 * i; }
  float c = cosT[t * 64 + i], s = sinT[t * 64 + i];
  size_t o = (size_t)row * 3072 + col;
  float x1 = b2f(QKV[o]), x2 = b2f(QKV[o + 1]);
  QKV[o]     = f2b(x1 * c - x2 * s);
  QKV[o + 1] = f2b(x1 * s + x2 * c);
}

// ---------------- fused SWA+meta GQA attention, 4-wave QBLK=64, swapped QK^T ----
// Raw barriers + counted vmcnt (loads genuinely span the compute phase now).
__global__ __launch_bounds__(256) void attn_kernel(const u16* __restrict__ QKV,
                                                   const u16* __restrict__ Vt,
                                                   u16* __restrict__ AO) {
  __shared__ __align__(16) u16 lK[2][64 * 128];   // [key][dh swz]  16KB x2
  __shared__ __align__(16) u16 lV[2][128 * 64];   // [dh][key swz]  16KB x2
  __shared__ __align__(16) u16 lP[4][16 * 70];    // per-wave P [q][key], stride 70
  const int tid = threadIdx.x, wave = tid >> 6, lane = tid & 63;
  const int lid = blockIdx.x;
  const int g = lid & 7;                 // (b,kv)
  const int b = g >> 2, kv = g & 3;
  const int h = kv * 4 + ((lid >> 3) & 3);
  const int qt = lid >> 5;               // 0..31
  const int q0 = qt * 64;
  const int qw = q0 + wave * 16;
  const size_t rowbase = (size_t)(b * 2048) * 3072;
  const u16* Qb = QKV + rowbase + h * 128;
  const u16* Kb = QKV + rowbase + 2048 + kv * 128;
  const u16* Vb = Vt + (size_t)g * 128 * 2048;

  bf16x8 qf[4];
  {
    const u16* qs = Qb + (size_t)(qw + (lane & 15)) * 3072 + (lane >> 4) * 8;
#pragma unroll
    for (int s = 0; s < 4; ++s) qf[s] = *(const bf16x8*)(qs + s * 32);
  }
  f32x4 oacc[8];
#pragma unroll
  for (int n = 0; n < 8; ++n) oacc[n] = (f32x4){0.f, 0.f, 0.f, 0.f};
  float m_run = -1e30f, l_run = 0.f;

  const int kt_lo = (q0 > 1023) ? ((q0 - 1023) >> 6) : 0;
  const int nt = (qt - kt_lo + 1) + (kt_lo > 0 ? 1 : 0);

  auto stageK = [&](int buf, int kb) {
#pragma unroll
    for (int p = 0; p < 4; ++p) {
      const int rr = p * 4 + (lane >> 4);
      const int sc_ = ((lane & 15) ^ (rr & 7)) * 8;
      load_lds16(Kb + (size_t)(kb + wave * 16 + rr) * 3072 + sc_,
                 &lK[buf][(wave * 16 + p * 4) * 128]);
    }
  };
  auto stageV = [&](int buf, int kb) {
#pragma unroll
    for (int p = 0; p < 4; ++p) {
      const int d = wave * 32 + p * 8 + (lane >> 3);
      const int sc_ = ((lane & 7) ^ (lane >> 3)) * 8;
      load_lds16(Vb + (size_t)d * 2048 + kb + sc_,
                 &lV[buf][(wave * 32 + p * 8) * 64]);
    }
  };

  stageK(0, 0);
  stageV(0, 0);

  const int qmine = qw + (lane & 15);
  int cur = 0;
  for (int it = 0; it < nt; ++it) {
    const int kt = (kt_lo > 0) ? (it == 0 ? 0 : kt_lo + it - 1) : it;
    const int kb = kt * 64;
    if (it + 1 < nt) {
      const int kbn = ((kt_lo > 0) ? (kt_lo + it) : (it + 1)) * 64;
      stageK(cur ^ 1, kbn);
      stageV(cur ^ 1, kbn);
      asm volatile("s_waitcnt vmcnt(8)" ::: "memory");
    } else {
      asm volatile("s_waitcnt vmcnt(0)" ::: "memory");
    }
    __builtin_amdgcn_s_barrier();          // buf[cur] ready (no drain)
    __builtin_amdgcn_sched_barrier(0);

    // S^T = K Q^T: D col=lane&15=q, row=(lane>>4)*4+j (+ct*16)
    f32x4 sc[4];
    __builtin_amdgcn_s_setprio(1);
#pragma unroll
    for (int ct = 0; ct < 4; ++ct) {
      f32x4 s = (f32x4){0.f, 0.f, 0.f, 0.f};
      const int kr = ct * 16 + (lane & 15);
#pragma unroll
      for (int ss = 0; ss < 4; ++ss) {
        const int ksl = (ss * 4 + (lane >> 4)) ^ (lane & 7);
        bf16x8 kf = *(const bf16x8*)&lK[cur][kr * 128 + ksl * 8];
        s = __builtin_amdgcn_mfma_f32_16x16x32_bf16(kf, qf[ss], s, 0, 0, 0);
      }
      sc[ct] = s;
    }
    __builtin_amdgcn_s_setprio(0);

    const float scale = 0.08838834764831845f;  // 1/sqrt(128)
#pragma unroll
    for (int ct = 0; ct < 4; ++ct) {
      const int kbase = kb + ct * 16 + ((lane >> 4) << 2);
#pragma unroll
      for (int j = 0; j < 4; ++j) {
        const int key = kbase + j;
        float sv = sc[ct][j] * scale;
        bool ok = (key < 16) || (key <= qmine && (qmine - key) < 1024);
        sc[ct][j] = ok ? sv : -1e30f;
      }
    }
    float mt = sc[0][0];
#pragma unroll
    for (int ct = 0; ct < 4; ++ct)
#pragma unroll
      for (int j = 0; j < 4; ++j) mt = fmaxf(mt, sc[ct][j]);
    mt = fmaxf(mt, __shfl_xor(mt, 16));
    mt = fmaxf(mt, __shfl_xor(mt, 32));
    const float mn = fmaxf(m_run, mt);
    const float alpha = __expf(m_run - mn);
    m_run = mn;
    float rs = 0.f;
#pragma unroll
    for (int ct = 0; ct < 4; ++ct)
#pragma unroll
      for (int j = 0; j < 4; ++j) {
        sc[ct][j] = __expf(sc[ct][j] - mn);
        rs += sc[ct][j];
      }
    rs += __shfl_xor(rs, 16);
    rs += __shfl_xor(rs, 32);
    l_run = l_run * alpha + rs;

    float abc[4];
#pragma unroll
    for (int j = 0; j < 4; ++j)
      abc[j] = __shfl(alpha, ((lane >> 4) << 2) + j, 16);
#pragma unroll
    for (int n = 0; n < 8; ++n)
#pragma unroll
      for (int j = 0; j < 4; ++j)
        oacc[n][j] *= abc[j];

    u16* Pw = &lP[wave][0];
#pragma unroll
    for (int ct = 0; ct < 4; ++ct)
#pragma unroll
      for (int j = 0; j < 4; ++j)
        Pw[(lane & 15) * 70 + ct * 16 + ((lane >> 4) << 2) + j] = f2b(sc[ct][j]);

    __builtin_amdgcn_s_setprio(1);
#pragma unroll
    for (int kss = 0; kss < 2; ++kss) {
      bf16x8 pa = *(const bf16x8*)&Pw[(lane & 15) * 70 + kss * 32 + (lane >> 4) * 8];
#pragma unroll
      for (int n = 0; n < 8; ++n) {
        const int vrow = n * 16 + (lane & 15);
        const int vsl = (kss * 4 + (lane >> 4)) ^ (lane & 7);
        bf16x8 vf = *(const bf16x8*)&lV[cur][vrow * 64 + vsl * 8];
        oacc[n] = __builtin_amdgcn_mfma_f32_16x16x32_bf16(pa, vf, oacc[n], 0, 0, 0);
      }
    }
    __builtin_amdgcn_s_setprio(0);
    __builtin_amdgcn_sched_barrier(0);
    __builtin_amdgcn_s_barrier();          // all waves done reading buf[cur]
    cur ^= 1;
  }
  const float linv = 1.0f / l_run;
  const int qrb = qw + ((lane >> 4) << 2);
#pragma unroll
  for (int j = 0; j < 4; ++j) {
    const float inv = __shfl(linv, ((lane >> 4) << 2) + j, 16);
    const size_t rowo = (size_t)(b * 2048 + qrb + j) * 2048 + h * 128;
#pragma unroll
    for (int n = 0; n < 8; ++n)
      AO[rowo + n * 16 + (lane & 15)] = f2b(oacc[n][j] * inv);
  }
}

extern "C" void kernel_launch(void* const* d_in, const int* in_sizes, int n_in,
                              void* d_out, int out_size, void* d_ws, size_t ws_size,
                              hipStream_t stream) {
  (void)in_sizes; (void)n_in; (void)out_size; (void)ws_size;
  const float* x  = (const float*)d_in[0];
  const float* wq = (const float*)d_in[1];
  const float* wk = (const float*)d_in[2];
  const float* wv = (const float*)d_in[3];
  const float* wo = (const float*)d_in[4];
  float* out = (float*)d_out;

  // workspace carve (~68 MB)
  u16* xb    = (u16*)d_ws;                         // [4096][2048]
  u16* wqkvT = xb    + (size_t)4096 * 2048;        // [3072][2048]
  u16* woT   = wqkvT + (size_t)3072 * 2048;        // [2048][2048]
  u16* QKV   = woT   + (size_t)2048 * 2048;        // [4096][3072]
  u16* Vt    = QKV   + (size_t)4096 * 3072;        // [8][128][2048]
  float* cosT = (float*)(Vt + (size_t)8 * 128 * 2048);  // [2048][64]
  float* sinT = cosT + 2048 * 64;
  u16* AO = xb;  // alias: xb dead after QKV GEMM

  pack_x_kernel<<<8192, 256, 0, stream>>>(x, xb);
  transpose_kernel<<<dim3(64, 64), 256, 0, stream>>>(wq, wqkvT, 2048, 2048);
  transpose_kernel<<<dim3(16, 64), 256, 0, stream>>>(wk, wqkvT + (size_t)2048 * 2048, 2048, 512);
  transpose_kernel<<<dim3(16, 64), 256, 0, stream>>>(wv, wqkvT + (size_t)2560 * 2048, 2048, 512);
  transpose_kernel<<<dim3(64, 64), 256, 0, stream>>>(wo, woT, 2048, 2048);
  rope_tables_kernel<<<512, 256, 0, stream>>>(cosT, sinT);
  gemm_bt_kernel<0><<<dim3(24, 32), 256, 0, stream>>>(xb, wqkvT, (void*)QKV, 4096, 3072, 2048);
  rope_kernel<<<20480, 256, 0, stream>>>(QKV, cosT, sinT);
  v_transpose_kernel<<<dim3(32, 4, 8), 256, 0, stream>>>(QKV, Vt);
  attn_kernel<<<1024, 256, 0, stream>>>(QKV, Vt, AO);
  gemm_bt_kernel<1><<<dim3(16, 32), 256, 0, stream>>>(AO, woT, (void*)out, 4096, 2048, 2048);
}

// Round 9
// 228.571 us; speedup vs baseline: 1.8054x; 1.0390x over previous
//
#include <hip/hip_runtime.h>
#include <cstdint>

typedef unsigned short u16;
typedef __attribute__((ext_vector_type(8))) short bf16x8;
typedef __attribute__((ext_vector_type(4))) float f32x4;

static __device__ __forceinline__ float b2f(u16 u) {
  union { unsigned int i; float f; } v; v.i = ((unsigned int)u) << 16; return v.f;
}
static __device__ __forceinline__ u16 f2b(float f) {
  union { float f; unsigned int i; } v; v.f = f;
  unsigned int r = (v.i + 0x7FFFu + ((v.i >> 16) & 1u)) >> 16;
  return (u16)r;
}
static __device__ __forceinline__ void load_lds16(const void* g, void* l) {
  __builtin_amdgcn_global_load_lds((const __attribute__((address_space(1))) void*)g,
                                   (__attribute__((address_space(3))) void*)l, 16, 0, 0);
}

// ---------------- pack x (fp32 -> bf16), 4 elems/thread ----------------
__global__ void pack_x_kernel(const float* __restrict__ x, u16* __restrict__ xb) {
  int idx = blockIdx.x * 256 + threadIdx.x;
  float4 v = ((const float4*)x)[idx];
  unsigned long long pk = (unsigned long long)f2b(v.x)
                        | ((unsigned long long)f2b(v.y) << 16)
                        | ((unsigned long long)f2b(v.z) << 32)
                        | ((unsigned long long)f2b(v.w) << 48);
  ((unsigned long long*)xb)[idx] = pk;
}

// ---------------- transpose fp32 [R][C] -> bf16 [C][R] ----------------
__global__ void transpose_kernel(const float* __restrict__ src, u16* __restrict__ dst,
                                 int R, int C) {
  __shared__ float tile[32][33];
  int tx = threadIdx.x & 31, ty = threadIdx.x >> 5;
  int c0 = blockIdx.x * 32, r0 = blockIdx.y * 32;
#pragma unroll
  for (int i = 0; i < 4; ++i)
    tile[ty + i * 8][tx] = src[(size_t)(r0 + ty + i * 8) * C + c0 + tx];
  __syncthreads();
#pragma unroll
  for (int i = 0; i < 4; ++i)
    dst[(size_t)(c0 + ty + i * 8) * R + r0 + tx] = f2b(tile[tx][ty + i * 8]);
}

// ---------------- V transpose: QKV V-cols -> Vt [b*4+kv][128 d][2048 t] ----------------
__global__ void v_transpose_kernel(const u16* __restrict__ QKV, u16* __restrict__ Vt) {
  __shared__ __align__(16) u16 tile[32][80];
  const int bkv = blockIdx.z;            // 0..7
  const int b = bkv >> 2, kv = bkv & 3;
  const int d0 = blockIdx.y * 32;        // 0..96
  const int t0 = blockIdx.x * 64;        // 0..1984
  const int tid = threadIdx.x;
  const int tr = tid >> 2, dc = tid & 3;
  bf16x8 vv = *(const bf16x8*)(QKV + (size_t)(b * 2048 + t0 + tr) * 3072 + 2560 + kv * 128 + d0 + dc * 8);
#pragma unroll
  for (int e = 0; e < 8; ++e) tile[dc * 8 + e][tr] = (u16)vv[e];
  __syncthreads();
  const int d = tid >> 3, tc = tid & 7;
  *(bf16x8*)(Vt + (size_t)(bkv * 128 + d0 + d) * 2048 + t0 + tc * 8) =
      *(const bf16x8*)&tile[d][tc * 8];
}

// ---------------- RoPE tables: [T][64] cos/sin ----------------
__global__ void rope_tables_kernel(float* __restrict__ cosT, float* __restrict__ sinT) {
  int idx = blockIdx.x * 256 + threadIdx.x;  // T*64
  int t = idx >> 6, i = idx & 63;
  float inv = powf(10000.0f, -(float)i * (1.0f / 64.0f));
  float a = (float)t * inv;
  cosT[idx] = cosf(a);
  sinT[idx] = sinf(a);
}

// ---------------- GEMM: C[M][N] = A[M][K] * BT[N][K]^T  (bf16 in, OUTF=0 bf16 / 1 fp32 out)
// Pipelined: depth-1 prefetch, counted vmcnt(8), raw barriers (no drain),
// chunk-XOR LDS swizzle (pre-swizzled global source / swizzled ds_read).
template <int OUTF>
__global__ __launch_bounds__(256) void gemm_bt_kernel(const u16* __restrict__ A,
                                                      const u16* __restrict__ BT,
                                                      void* __restrict__ Cv,
                                                      int M, int N, int K) {
  __shared__ __align__(16) u16 lA[2][128 * 64];
  __shared__ __align__(16) u16 lB[2][128 * 64];
  const int tid = threadIdx.x;
  const int wave = tid >> 6, lane = tid & 63;
  const int wr = wave >> 1, wc = wave & 1;
  const int row0 = blockIdx.y * 128, col0 = blockIdx.x * 128;
  f32x4 acc[4][4];
#pragma unroll
  for (int m = 0; m < 4; ++m)
#pragma unroll
    for (int n = 0; n < 4; ++n) acc[m][n] = (f32x4){0.f, 0.f, 0.f, 0.f};
  const int rb = wave * 32;
  const int lrow = lane >> 3;          // 0..7 (row within 8-row stage group)
  const int schk = ((lane & 7) ^ lrow) * 8;  // pre-swizzled source chunk
  const u16* pA = A + (size_t)(row0 + rb + lrow) * K + schk;
  const u16* pB = BT + (size_t)(col0 + rb + lrow) * K + schk;
  const int NT = K >> 6;

  // prologue: stage tile 0 into buf 0 (8 ops in flight)
#pragma unroll
  for (int i = 0; i < 4; ++i) {
    load_lds16(pA + (size_t)i * 8 * K, &lA[0][(rb + i * 8) * 64]);
    load_lds16(pB + (size_t)i * 8 * K, &lB[0][(rb + i * 8) * 64]);
  }

  for (int t = 0; t < NT; ++t) {
    const int cur = t & 1;
    if (t + 1 < NT) {
      const size_t k1 = (size_t)(t + 1) << 6;
#pragma unroll
      for (int i = 0; i < 4; ++i) {
        load_lds16(pA + k1 + (size_t)i * 8 * K, &lA[cur ^ 1][(rb + i * 8) * 64]);
        load_lds16(pB + k1 + (size_t)i * 8 * K, &lB[cur ^ 1][(rb + i * 8) * 64]);
      }
      asm volatile("s_waitcnt vmcnt(8)" ::: "memory");  // tile t landed; t+1 in flight
    } else {
      asm volatile("s_waitcnt vmcnt(0)" ::: "memory");
    }
    __builtin_amdgcn_s_barrier();            // buf[cur] ready for all waves (no drain)
    __builtin_amdgcn_sched_barrier(0);
    __builtin_amdgcn_s_setprio(1);
#pragma unroll
    for (int ks = 0; ks < 2; ++ks) {
      bf16x8 af[4], bfr[4];
      const int sl = ((ks * 4 + (lane >> 4)) ^ (lane & 7)) * 8;  // swizzled read slot
#pragma unroll
      for (int m = 0; m < 4; ++m)
        af[m] = *(const bf16x8*)&lA[cur][(wr * 64 + m * 16 + (lane & 15)) * 64 + sl];
#pragma unroll
      for (int n = 0; n < 4; ++n)
        bfr[n] = *(const bf16x8*)&lB[cur][(wc * 64 + n * 16 + (lane & 15)) * 64 + sl];
#pragma unroll
      for (int m = 0; m < 4; ++m)
#pragma unroll
        for (int n = 0; n < 4; ++n)
          acc[m][n] = __builtin_amdgcn_mfma_f32_16x16x32_bf16(af[m], bfr[n], acc[m][n], 0, 0, 0);
    }
    __builtin_amdgcn_s_setprio(0);
    __builtin_amdgcn_sched_barrier(0);
    __builtin_amdgcn_s_barrier();            // all waves done reading buf[cur]
  }
  const int rbase = row0 + wr * 64 + ((lane >> 4) << 2);
  const int cbase = col0 + wc * 64 + (lane & 15);
#pragma unroll
  for (int m = 0; m < 4; ++m)
#pragma unroll
    for (int n = 0; n < 4; ++n)
#pragma unroll
      for (int j = 0; j < 4; ++j) {
        size_t off = (size_t)(rbase + m * 16 + j) * N + cbase + n * 16;
        if (OUTF == 0) ((u16*)Cv)[off] = f2b(acc[m][n][j]);
        else           ((float*)Cv)[off] = acc[m][n][j];
      }
}

// ---------------- RoPE in-place on Q,K columns of QKV [4096][3072] ----------------
__global__ void rope_kernel(u16* __restrict__ QKV, const float* __restrict__ cosT,
                            const float* __restrict__ sinT) {
  int idx = blockIdx.x * 256 + threadIdx.x;  // 4096*1280
  int row = idx / 1280;
  int rem = idx - row * 1280;
  int t = row & 2047;
  int i = rem & 63;
  int col;
  if (rem < 1024) col = (rem >> 6) * 128 + 2 * i;
  else { int r2 = rem - 1024; col = 2048 + (r2 >> 6) * 128 + 2 * i; }
  float c = cosT[t * 64 + i], s = sinT[t * 64 + i];
  size_t o = (size_t)row * 3072 + col;
  float x1 = b2f(QKV[o]), x2 = b2f(QKV[o + 1]);
  QKV[o]     = f2b(x1 * c - x2 * s);
  QKV[o + 1] = f2b(x1 * s + x2 * c);
}

// ---------------- fused SWA+meta GQA attention, 4-wave QBLK=64, swapped QK^T ----
// Round-5 softmax (scaled domain, unconditional rescale, scalar P writes),
// plus ONLY the interior-tile mask skip (scale preserved in skip branch).
__global__ __launch_bounds__(256) void attn_kernel(const u16* __restrict__ QKV,
                                                   const u16* __restrict__ Vt,
                                                   u16* __restrict__ AO) {
  __shared__ __align__(16) u16 lK[2][64 * 128];   // [key][dh swz]  16KB x2
  __shared__ __align__(16) u16 lV[2][128 * 64];   // [dh][key swz]  16KB x2
  __shared__ __align__(16) u16 lP[4][16 * 70];    // per-wave P [q][key], stride 70
  const int tid = threadIdx.x, wave = tid >> 6, lane = tid & 63;
  const int lid = blockIdx.x;
  const int g = lid & 7;                 // (b,kv)
  const int b = g >> 2, kv = g & 3;
  const int h = kv * 4 + ((lid >> 3) & 3);
  const int qt = lid >> 5;               // 0..31
  const int q0 = qt * 64;
  const int qw = q0 + wave * 16;
  const size_t rowbase = (size_t)(b * 2048) * 3072;
  const u16* Qb = QKV + rowbase + h * 128;
  const u16* Kb = QKV + rowbase + 2048 + kv * 128;
  const u16* Vb = Vt + (size_t)g * 128 * 2048;

  bf16x8 qf[4];
  {
    const u16* qs = Qb + (size_t)(qw + (lane & 15)) * 3072 + (lane >> 4) * 8;
#pragma unroll
    for (int s = 0; s < 4; ++s) qf[s] = *(const bf16x8*)(qs + s * 32);
  }
  f32x4 oacc[8];
#pragma unroll
  for (int n = 0; n < 8; ++n) oacc[n] = (f32x4){0.f, 0.f, 0.f, 0.f};
  float m_run = -1e30f, l_run = 0.f;

  const int kt_lo = (q0 > 1023) ? ((q0 - 1023) >> 6) : 0;
  const int nt = (qt - kt_lo + 1) + (kt_lo > 0 ? 1 : 0);

  auto stageK = [&](int buf, int kb) {
#pragma unroll
    for (int p = 0; p < 4; ++p) {
      const int rr = p * 4 + (lane >> 4);
      const int sc_ = ((lane & 15) ^ (rr & 7)) * 8;
      load_lds16(Kb + (size_t)(kb + wave * 16 + rr) * 3072 + sc_,
                 &lK[buf][(wave * 16 + p * 4) * 128]);
    }
  };
  auto stageV = [&](int buf, int kb) {
#pragma unroll
    for (int p = 0; p < 4; ++p) {
      const int d = wave * 32 + p * 8 + (lane >> 3);
      const int sc_ = ((lane & 7) ^ (lane >> 3)) * 8;
      load_lds16(Vb + (size_t)d * 2048 + kb + sc_,
                 &lV[buf][(wave * 32 + p * 8) * 64]);
    }
  };

  stageK(0, 0);
  stageV(0, 0);

  const int qmine = qw + (lane & 15);
  int cur = 0;
  for (int it = 0; it < nt; ++it) {
    const int kt = (kt_lo > 0) ? (it == 0 ? 0 : kt_lo + it - 1) : it;
    const int kb = kt * 64;
    if (it + 1 < nt) {
      const int kbn = ((kt_lo > 0) ? (kt_lo + it) : (it + 1)) * 64;
      stageK(cur ^ 1, kbn);
      stageV(cur ^ 1, kbn);
      asm volatile("s_waitcnt vmcnt(8)" ::: "memory");
    } else {
      asm volatile("s_waitcnt vmcnt(0)" ::: "memory");
    }
    __builtin_amdgcn_s_barrier();          // buf[cur] ready (no drain)
    __builtin_amdgcn_sched_barrier(0);

    // S^T = K Q^T: D col=lane&15=q, row=(lane>>4)*4+j (+ct*16)
    f32x4 sc[4];
    __builtin_amdgcn_s_setprio(1);
#pragma unroll
    for (int ct = 0; ct < 4; ++ct) {
      f32x4 s = (f32x4){0.f, 0.f, 0.f, 0.f};
      const int kr = ct * 16 + (lane & 15);
#pragma unroll
      for (int ss = 0; ss < 4; ++ss) {
        const int ksl = (ss * 4 + (lane >> 4)) ^ (lane & 7);
        bf16x8 kf = *(const bf16x8*)&lK[cur][kr * 128 + ksl * 8];
        s = __builtin_amdgcn_mfma_f32_16x16x32_bf16(kf, qf[ss], s, 0, 0, 0);
      }
      sc[ct] = s;
    }
    __builtin_amdgcn_s_setprio(0);

    const float scale = 0.08838834764831845f;  // 1/sqrt(128)
    // interior tiles: all (q,key) pairs in-window -> scale only, no mask ops
    const bool nomask = (kb + 63 <= qw) && (qw + 15 - kb <= 1023);
    if (nomask) {
#pragma unroll
      for (int ct = 0; ct < 4; ++ct)
#pragma unroll
        for (int j = 0; j < 4; ++j)
          sc[ct][j] *= scale;
    } else {
#pragma unroll
      for (int ct = 0; ct < 4; ++ct) {
        const int kbase = kb + ct * 16 + ((lane >> 4) << 2);
#pragma unroll
        for (int j = 0; j < 4; ++j) {
          const int key = kbase + j;
          float sv = sc[ct][j] * scale;
          bool ok = (key < 16) || (key <= qmine && (qmine - key) < 1024);
          sc[ct][j] = ok ? sv : -1e30f;
        }
      }
    }
    // row max: in-register tree + 2 cross-group shfl
    float mt = sc[0][0];
#pragma unroll
    for (int ct = 0; ct < 4; ++ct)
#pragma unroll
      for (int j = 0; j < 4; ++j) mt = fmaxf(mt, sc[ct][j]);
    mt = fmaxf(mt, __shfl_xor(mt, 16));
    mt = fmaxf(mt, __shfl_xor(mt, 32));
    const float mn = fmaxf(m_run, mt);
    const float alpha = __expf(m_run - mn);
    m_run = mn;
    float rs = 0.f;
#pragma unroll
    for (int ct = 0; ct < 4; ++ct)
#pragma unroll
      for (int j = 0; j < 4; ++j) {
        sc[ct][j] = __expf(sc[ct][j] - mn);
        rs += sc[ct][j];
      }
    rs += __shfl_xor(rs, 16);
    rs += __shfl_xor(rs, 32);
    l_run = l_run * alpha + rs;

    // broadcast alpha to the q-rows this lane accumulates in oacc
    float abc[4];
#pragma unroll
    for (int j = 0; j < 4; ++j)
      abc[j] = __shfl(alpha, ((lane >> 4) << 2) + j, 16);
#pragma unroll
    for (int n = 0; n < 8; ++n)
#pragma unroll
      for (int j = 0; j < 4; ++j)
        oacc[n][j] *= abc[j];

    // write P tile: P[q=lane&15][key = ct*16 + (lane>>4)*4 + j], stride 70
    u16* Pw = &lP[wave][0];
#pragma unroll
    for (int ct = 0; ct < 4; ++ct)
#pragma unroll
      for (int j = 0; j < 4; ++j)
        Pw[(lane & 15) * 70 + ct * 16 + ((lane >> 4) << 2) + j] = f2b(sc[ct][j]);

    __builtin_amdgcn_s_setprio(1);
#pragma unroll
    for (int kss = 0; kss < 2; ++kss) {
      bf16x8 pa = *(const bf16x8*)&Pw[(lane & 15) * 70 + kss * 32 + (lane >> 4) * 8];
#pragma unroll
      for (int n = 0; n < 8; ++n) {
        const int vrow = n * 16 + (lane & 15);
        const int vsl = (kss * 4 + (lane >> 4)) ^ (lane & 7);
        bf16x8 vf = *(const bf16x8*)&lV[cur][vrow * 64 + vsl * 8];
        oacc[n] = __builtin_amdgcn_mfma_f32_16x16x32_bf16(pa, vf, oacc[n], 0, 0, 0);
      }
    }
    __builtin_amdgcn_s_setprio(0);
    __builtin_amdgcn_sched_barrier(0);
    __builtin_amdgcn_s_barrier();          // all waves done reading buf[cur]
    cur ^= 1;
  }
  const float linv = 1.0f / l_run;
  const int qrb = qw + ((lane >> 4) << 2);
#pragma unroll
  for (int j = 0; j < 4; ++j) {
    const float inv = __shfl(linv, ((lane >> 4) << 2) + j, 16);
    const size_t rowo = (size_t)(b * 2048 + qrb + j) * 2048 + h * 128;
#pragma unroll
    for (int n = 0; n < 8; ++n)
      AO[rowo + n * 16 + (lane & 15)] = f2b(oacc[n][j] * inv);
  }
}

extern "C" void kernel_launch(void* const* d_in, const int* in_sizes, int n_in,
                              void* d_out, int out_size, void* d_ws, size_t ws_size,
                              hipStream_t stream) {
  (void)in_sizes; (void)n_in; (void)out_size; (void)ws_size;
  const float* x  = (const float*)d_in[0];
  const float* wq = (const float*)d_in[1];
  const float* wk = (const float*)d_in[2];
  const float* wv = (const float*)d_in[3];
  const float* wo = (const float*)d_in[4];
  float* out = (float*)d_out;

  // workspace carve (~68 MB)
  u16* xb    = (u16*)d_ws;                         // [4096][2048]
  u16* wqkvT = xb    + (size_t)4096 * 2048;        // [3072][2048]
  u16* woT   = wqkvT + (size_t)3072 * 2048;        // [2048][2048]
  u16* QKV   = woT   + (size_t)2048 * 2048;        // [4096][3072]
  u16* Vt    = QKV   + (size_t)4096 * 3072;        // [8][128][2048]
  float* cosT = (float*)(Vt + (size_t)8 * 128 * 2048);  // [2048][64]
  float* sinT = cosT + 2048 * 64;
  u16* AO = xb;  // alias: xb dead after QKV GEMM

  pack_x_kernel<<<8192, 256, 0, stream>>>(x, xb);
  transpose_kernel<<<dim3(64, 64), 256, 0, stream>>>(wq, wqkvT, 2048, 2048);
  transpose_kernel<<<dim3(16, 64), 256, 0, stream>>>(wk, wqkvT + (size_t)2048 * 2048, 2048, 512);
  transpose_kernel<<<dim3(16, 64), 256, 0, stream>>>(wv, wqkvT + (size_t)2560 * 2048, 2048, 512);
  transpose_kernel<<<dim3(64, 64), 256, 0, stream>>>(wo, woT, 2048, 2048);
  rope_tables_kernel<<<512, 256, 0, stream>>>(cosT, sinT);
  gemm_bt_kernel<0><<<dim3(24, 32), 256, 0, stream>>>(xb, wqkvT, (void*)QKV, 4096, 3072, 2048);
  rope_kernel<<<20480, 256, 0, stream>>>(QKV, cosT, sinT);
  v_transpose_kernel<<<dim3(32, 4, 8), 256, 0, stream>>>(QKV, Vt);
  attn_kernel<<<1024, 256, 0, stream>>>(QKV, Vt, AO);
  gemm_bt_kernel<1><<<dim3(16, 32), 256, 0, stream>>>(AO, woT, (void*)out, 4096, 2048, 2048);
}

// Round 10
// 213.106 us; speedup vs baseline: 1.9364x; 1.0726x over previous
//
#include <hip/hip_runtime.h>
#include <cstdint>

typedef unsigned short u16;
typedef __attribute__((ext_vector_type(8))) short bf16x8;
typedef __attribute__((ext_vector_type(4))) float f32x4;

static __device__ __forceinline__ float b2f(u16 u) {
  union { unsigned int i; float f; } v; v.i = ((unsigned int)u) << 16; return v.f;
}
static __device__ __forceinline__ u16 f2b(float f) {
  union { float f; unsigned int i; } v; v.f = f;
  unsigned int r = (v.i + 0x7FFFu + ((v.i >> 16) & 1u)) >> 16;
  return (u16)r;
}
static __device__ __forceinline__ unsigned int cvt_pk_bf16(float lo, float hi) {
  unsigned int r;
  asm("v_cvt_pk_bf16_f32 %0, %1, %2" : "=v"(r) : "v"(lo), "v"(hi));
  return r;
}
static __device__ __forceinline__ void load_lds16(const void* g, void* l) {
  __builtin_amdgcn_global_load_lds((const __attribute__((address_space(1))) void*)g,
                                   (__attribute__((address_space(3))) void*)l, 16, 0, 0);
}

// ---------------- pack x (fp32 -> bf16), 4 elems/thread ----------------
__global__ void pack_x_kernel(const float* __restrict__ x, u16* __restrict__ xb) {
  int idx = blockIdx.x * 256 + threadIdx.x;
  float4 v = ((const float4*)x)[idx];
  unsigned long long pk = (unsigned long long)f2b(v.x)
                        | ((unsigned long long)f2b(v.y) << 16)
                        | ((unsigned long long)f2b(v.z) << 32)
                        | ((unsigned long long)f2b(v.w) << 48);
  ((unsigned long long*)xb)[idx] = pk;
}

// ---------------- transpose fp32 [R][C] -> bf16 [C][R] ----------------
__global__ void transpose_kernel(const float* __restrict__ src, u16* __restrict__ dst,
                                 int R, int C) {
  __shared__ float tile[32][33];
  int tx = threadIdx.x & 31, ty = threadIdx.x >> 5;
  int c0 = blockIdx.x * 32, r0 = blockIdx.y * 32;
#pragma unroll
  for (int i = 0; i < 4; ++i)
    tile[ty + i * 8][tx] = src[(size_t)(r0 + ty + i * 8) * C + c0 + tx];
  __syncthreads();
#pragma unroll
  for (int i = 0; i < 4; ++i)
    dst[(size_t)(c0 + ty + i * 8) * R + r0 + tx] = f2b(tile[tx][ty + i * 8]);
}

// ---------------- V transpose: QKV V-cols -> Vt [b*4+kv][128 d][2048 t] ----------------
__global__ void v_transpose_kernel(const u16* __restrict__ QKV, u16* __restrict__ Vt) {
  __shared__ __align__(16) u16 tile[32][80];
  const int bkv = blockIdx.z;            // 0..7
  const int b = bkv >> 2, kv = bkv & 3;
  const int d0 = blockIdx.y * 32;        // 0..96
  const int t0 = blockIdx.x * 64;        // 0..1984
  const int tid = threadIdx.x;
  const int tr = tid >> 2, dc = tid & 3;
  bf16x8 vv = *(const bf16x8*)(QKV + (size_t)(b * 2048 + t0 + tr) * 3072 + 2560 + kv * 128 + d0 + dc * 8);
#pragma unroll
  for (int e = 0; e < 8; ++e) tile[dc * 8 + e][tr] = (u16)vv[e];
  __syncthreads();
  const int d = tid >> 3, tc = tid & 7;
  *(bf16x8*)(Vt + (size_t)(bkv * 128 + d0 + d) * 2048 + t0 + tc * 8) =
      *(const bf16x8*)&tile[d][tc * 8];
}

// ---------------- RoPE tables: [T][64] cos/sin ----------------
__global__ void rope_tables_kernel(float* __restrict__ cosT, float* __restrict__ sinT) {
  int idx = blockIdx.x * 256 + threadIdx.x;  // T*64
  int t = idx >> 6, i = idx & 63;
  float inv = powf(10000.0f, -(float)i * (1.0f / 64.0f));
  float a = (float)t * inv;
  cosT[idx] = cosf(a);
  sinT[idx] = sinf(a);
}

// ---------------- GEMM: C[M][N] = A[M][K] * BT[N][K]^T  (bf16 in, OUTF=0 bf16 / 1 fp32 out)
// Pipelined: depth-1 prefetch, counted vmcnt(8), raw barriers (no drain),
// chunk-XOR LDS swizzle (pre-swizzled global source / swizzled ds_read).
// NOTE: no XCD remap — quarantined (rounds 6-8 deterministic failure, cause unresolved).
template <int OUTF>
__global__ __launch_bounds__(256) void gemm_bt_kernel(const u16* __restrict__ A,
                                                      const u16* __restrict__ BT,
                                                      void* __restrict__ Cv,
                                                      int M, int N, int K) {
  __shared__ __align__(16) u16 lA[2][128 * 64];
  __shared__ __align__(16) u16 lB[2][128 * 64];
  const int tid = threadIdx.x;
  const int wave = tid >> 6, lane = tid & 63;
  const int wr = wave >> 1, wc = wave & 1;
  const int row0 = blockIdx.y * 128, col0 = blockIdx.x * 128;
  f32x4 acc[4][4];
#pragma unroll
  for (int m = 0; m < 4; ++m)
#pragma unroll
    for (int n = 0; n < 4; ++n) acc[m][n] = (f32x4){0.f, 0.f, 0.f, 0.f};
  const int rb = wave * 32;
  const int lrow = lane >> 3;          // 0..7 (row within 8-row stage group)
  const int schk = ((lane & 7) ^ lrow) * 8;  // pre-swizzled source chunk
  const u16* pA = A + (size_t)(row0 + rb + lrow) * K + schk;
  const u16* pB = BT + (size_t)(col0 + rb + lrow) * K + schk;
  const int NT = K >> 6;

  // prologue: stage tile 0 into buf 0 (8 ops in flight)
#pragma unroll
  for (int i = 0; i < 4; ++i) {
    load_lds16(pA + (size_t)i * 8 * K, &lA[0][(rb + i * 8) * 64]);
    load_lds16(pB + (size_t)i * 8 * K, &lB[0][(rb + i * 8) * 64]);
  }

  for (int t = 0; t < NT; ++t) {
    const int cur = t & 1;
    if (t + 1 < NT) {
      const size_t k1 = (size_t)(t + 1) << 6;
#pragma unroll
      for (int i = 0; i < 4; ++i) {
        load_lds16(pA + k1 + (size_t)i * 8 * K, &lA[cur ^ 1][(rb + i * 8) * 64]);
        load_lds16(pB + k1 + (size_t)i * 8 * K, &lB[cur ^ 1][(rb + i * 8) * 64]);
      }
      asm volatile("s_waitcnt vmcnt(8)" ::: "memory");  // tile t landed; t+1 in flight
    } else {
      asm volatile("s_waitcnt vmcnt(0)" ::: "memory");
    }
    __builtin_amdgcn_s_barrier();            // buf[cur] ready for all waves (no drain)
    __builtin_amdgcn_sched_barrier(0);
    __builtin_amdgcn_s_setprio(1);
#pragma unroll
    for (int ks = 0; ks < 2; ++ks) {
      bf16x8 af[4], bfr[4];
      const int sl = ((ks * 4 + (lane >> 4)) ^ (lane & 7)) * 8;  // swizzled read slot
#pragma unroll
      for (int m = 0; m < 4; ++m)
        af[m] = *(const bf16x8*)&lA[cur][(wr * 64 + m * 16 + (lane & 15)) * 64 + sl];
#pragma unroll
      for (int n = 0; n < 4; ++n)
        bfr[n] = *(const bf16x8*)&lB[cur][(wc * 64 + n * 16 + (lane & 15)) * 64 + sl];
#pragma unroll
      for (int m = 0; m < 4; ++m)
#pragma unroll
        for (int n = 0; n < 4; ++n)
          acc[m][n] = __builtin_amdgcn_mfma_f32_16x16x32_bf16(af[m], bfr[n], acc[m][n], 0, 0, 0);
    }
    __builtin_amdgcn_s_setprio(0);
    __builtin_amdgcn_sched_barrier(0);
    __builtin_amdgcn_s_barrier();            // all waves done reading buf[cur]
  }
  const int rbase = row0 + wr * 64 + ((lane >> 4) << 2);
  const int cbase = col0 + wc * 64 + (lane & 15);
#pragma unroll
  for (int m = 0; m < 4; ++m)
#pragma unroll
    for (int n = 0; n < 4; ++n)
#pragma unroll
      for (int j = 0; j < 4; ++j) {
        size_t off = (size_t)(rbase + m * 16 + j) * N + cbase + n * 16;
        if (OUTF == 0) ((u16*)Cv)[off] = f2b(acc[m][n][j]);
        else           ((float*)Cv)[off] = acc[m][n][j];
      }
}

// ---------------- RoPE in-place on Q,K columns of QKV [4096][3072] ----------------
__global__ void rope_kernel(u16* __restrict__ QKV, const float* __restrict__ cosT,
                            const float* __restrict__ sinT) {
  int idx = blockIdx.x * 256 + threadIdx.x;  // 4096*1280
  int row = idx / 1280;
  int rem = idx - row * 1280;
  int t = row & 2047;
  int i = rem & 63;
  int col;
  if (rem < 1024) col = (rem >> 6) * 128 + 2 * i;
  else { int r2 = rem - 1024; col = 2048 + (r2 >> 6) * 128 + 2 * i; }
  float c = cosT[t * 64 + i], s = sinT[t * 64 + i];
  size_t o = (size_t)row * 3072 + col;
  float x1 = b2f(QKV[o]), x2 = b2f(QKV[o + 1]);
  QKV[o]     = f2b(x1 * c - x2 * s);
  QKV[o + 1] = f2b(x1 * s + x2 * c);
}

// ---------------- fused SWA+meta GQA attention, 4-wave QBLK=64, swapped QK^T ----
// Round-9 softmax (scaled domain, unconditional rescale) + interior mask skip.
// This round: SINGLE-buffered K/V (LDS ~41 KB -> 3 blocks/CU), heavy-first qt
// ordering (qt = 31 - lid>>5), cvt_pk packed P-writes (layout proven == scalar).
__global__ __launch_bounds__(256) void attn_kernel(const u16* __restrict__ QKV,
                                                   const u16* __restrict__ Vt,
                                                   u16* __restrict__ AO) {
  __shared__ __align__(16) u16 lK[64 * 128];      // [key][dh swz]  16KB
  __shared__ __align__(16) u16 lV[128 * 64];      // [dh][key swz]  16KB
  __shared__ __align__(16) u16 lP[4][16 * 70];    // per-wave P [q][key], stride 70
  const int tid = threadIdx.x, wave = tid >> 6, lane = tid & 63;
  const int lid = blockIdx.x;
  const int g = lid & 7;                 // (b,kv) -> same-XCD L2 affinity
  const int b = g >> 2, kv = g & 3;
  const int h = kv * 4 + ((lid >> 3) & 3);
  const int qt = 31 - (lid >> 5);        // heavy blocks (large qt) first
  const int q0 = qt * 64;
  const int qw = q0 + wave * 16;
  const size_t rowbase = (size_t)(b * 2048) * 3072;
  const u16* Qb = QKV + rowbase + h * 128;
  const u16* Kb = QKV + rowbase + 2048 + kv * 128;
  const u16* Vb = Vt + (size_t)g * 128 * 2048;

  bf16x8 qf[4];
  {
    const u16* qs = Qb + (size_t)(qw + (lane & 15)) * 3072 + (lane >> 4) * 8;
#pragma unroll
    for (int s = 0; s < 4; ++s) qf[s] = *(const bf16x8*)(qs + s * 32);
  }
  f32x4 oacc[8];
#pragma unroll
  for (int n = 0; n < 8; ++n) oacc[n] = (f32x4){0.f, 0.f, 0.f, 0.f};
  float m_run = -1e30f, l_run = 0.f;

  const int kt_lo = (q0 > 1023) ? ((q0 - 1023) >> 6) : 0;
  const int nt = (qt - kt_lo + 1) + (kt_lo > 0 ? 1 : 0);

  auto stageK = [&](int kb) {
#pragma unroll
    for (int p = 0; p < 4; ++p) {
      const int rr = p * 4 + (lane >> 4);
      const int sc_ = ((lane & 15) ^ (rr & 7)) * 8;
      load_lds16(Kb + (size_t)(kb + wave * 16 + rr) * 3072 + sc_,
                 &lK[(wave * 16 + p * 4) * 128]);
    }
  };
  auto stageV = [&](int kb) {
#pragma unroll
    for (int p = 0; p < 4; ++p) {
      const int d = wave * 32 + p * 8 + (lane >> 3);
      const int sc_ = ((lane & 7) ^ (lane >> 3)) * 8;
      load_lds16(Vb + (size_t)d * 2048 + kb + sc_,
                 &lV[(wave * 32 + p * 8) * 64]);
    }
  };

  const int qmine = qw + (lane & 15);
  for (int it = 0; it < nt; ++it) {
    const int kt = (kt_lo > 0) ? (it == 0 ? 0 : kt_lo + it - 1) : it;
    const int kb = kt * 64;
    // single-buffer stage: issue, drain own loads, barrier -> tile ready
    stageK(kb);
    stageV(kb);
    asm volatile("s_waitcnt vmcnt(0)" ::: "memory");
    __builtin_amdgcn_s_barrier();
    __builtin_amdgcn_sched_barrier(0);

    // S^T = K Q^T: D col=lane&15=q, row=(lane>>4)*4+j (+ct*16)
    f32x4 sc[4];
    __builtin_amdgcn_s_setprio(1);
#pragma unroll
    for (int ct = 0; ct < 4; ++ct) {
      f32x4 s = (f32x4){0.f, 0.f, 0.f, 0.f};
      const int kr = ct * 16 + (lane & 15);
#pragma unroll
      for (int ss = 0; ss < 4; ++ss) {
        const int ksl = (ss * 4 + (lane >> 4)) ^ (lane & 7);
        bf16x8 kf = *(const bf16x8*)&lK[kr * 128 + ksl * 8];
        s = __builtin_amdgcn_mfma_f32_16x16x32_bf16(kf, qf[ss], s, 0, 0, 0);
      }
      sc[ct] = s;
    }
    __builtin_amdgcn_s_setprio(0);

    const float scale = 0.08838834764831845f;  // 1/sqrt(128)
    // interior tiles: all (q,key) pairs in-window -> scale only, no mask ops
    const bool nomask = (kb + 63 <= qw) && (qw + 15 - kb <= 1023);
    if (nomask) {
#pragma unroll
      for (int ct = 0; ct < 4; ++ct)
#pragma unroll
        for (int j = 0; j < 4; ++j)
          sc[ct][j] *= scale;
    } else {
#pragma unroll
      for (int ct = 0; ct < 4; ++ct) {
        const int kbase = kb + ct * 16 + ((lane >> 4) << 2);
#pragma unroll
        for (int j = 0; j < 4; ++j) {
          const int key = kbase + j;
          float sv = sc[ct][j] * scale;
          bool ok = (key < 16) || (key <= qmine && (qmine - key) < 1024);
          sc[ct][j] = ok ? sv : -1e30f;
        }
      }
    }
    // row max: in-register tree + 2 cross-group shfl
    float mt = sc[0][0];
#pragma unroll
    for (int ct = 0; ct < 4; ++ct)
#pragma unroll
      for (int j = 0; j < 4; ++j) mt = fmaxf(mt, sc[ct][j]);
    mt = fmaxf(mt, __shfl_xor(mt, 16));
    mt = fmaxf(mt, __shfl_xor(mt, 32));
    const float mn = fmaxf(m_run, mt);
    const float alpha = __expf(m_run - mn);
    m_run = mn;
    float rs = 0.f;
#pragma unroll
    for (int ct = 0; ct < 4; ++ct)
#pragma unroll
      for (int j = 0; j < 4; ++j) {
        sc[ct][j] = __expf(sc[ct][j] - mn);
        rs += sc[ct][j];
      }
    rs += __shfl_xor(rs, 16);
    rs += __shfl_xor(rs, 32);
    l_run = l_run * alpha + rs;

    // broadcast alpha to the q-rows this lane accumulates in oacc
    float abc[4];
#pragma unroll
    for (int j = 0; j < 4; ++j)
      abc[j] = __shfl(alpha, ((lane >> 4) << 2) + j, 16);
#pragma unroll
    for (int n = 0; n < 8; ++n)
#pragma unroll
      for (int j = 0; j < 4; ++j)
        oacc[n][j] *= abc[j];

    // packed P write: cvt_pk pairs -> b32 stores; layout == scalar path
    // (keys ct*16 + hi*4 + {0..3} for q-row lane&15; proven identical rounds 8/9)
    u16* Pw = &lP[wave][0];
    const int pb = (lane & 15) * 70 + ((lane >> 4) << 2);
#pragma unroll
    for (int ct = 0; ct < 4; ++ct) {
      unsigned int w0 = cvt_pk_bf16(sc[ct][0], sc[ct][1]);
      unsigned int w1 = cvt_pk_bf16(sc[ct][2], sc[ct][3]);
      *(unsigned int*)&Pw[pb + ct * 16]     = w0;
      *(unsigned int*)&Pw[pb + ct * 16 + 2] = w1;
    }

    __builtin_amdgcn_s_setprio(1);
#pragma unroll
    for (int kss = 0; kss < 2; ++kss) {
      bf16x8 pa = *(const bf16x8*)&Pw[(lane & 15) * 70 + kss * 32 + (lane >> 4) * 8];
#pragma unroll
      for (int n = 0; n < 8; ++n) {
        const int vrow = n * 16 + (lane & 15);
        const int vsl = (kss * 4 + (lane >> 4)) ^ (lane & 7);
        bf16x8 vf = *(const bf16x8*)&lV[vrow * 64 + vsl * 8];
        oacc[n] = __builtin_amdgcn_mfma_f32_16x16x32_bf16(pa, vf, oacc[n], 0, 0, 0);
      }
    }
    __builtin_amdgcn_s_setprio(0);
    __builtin_amdgcn_sched_barrier(0);
    __builtin_amdgcn_s_barrier();          // all waves done reading lK/lV before restage
  }
  const float linv = 1.0f / l_run;
  const int qrb = qw + ((lane >> 4) << 2);
#pragma unroll
  for (int j = 0; j < 4; ++j) {
    const float inv = __shfl(linv, ((lane >> 4) << 2) + j, 16);
    const size_t rowo = (size_t)(b * 2048 + qrb + j) * 2048 + h * 128;
#pragma unroll
    for (int n = 0; n < 8; ++n)
      AO[rowo + n * 16 + (lane & 15)] = f2b(oacc[n][j] * inv);
  }
}

extern "C" void kernel_launch(void* const* d_in, const int* in_sizes, int n_in,
                              void* d_out, int out_size, void* d_ws, size_t ws_size,
                              hipStream_t stream) {
  (void)in_sizes; (void)n_in; (void)out_size; (void)ws_size;
  const float* x  = (const float*)d_in[0];
  const float* wq = (const float*)d_in[1];
  const float* wk = (const float*)d_in[2];
  const float* wv = (const float*)d_in[3];
  const float* wo = (const float*)d_in[4];
  float* out = (float*)d_out;

  // workspace carve (~68 MB)
  u16* xb    = (u16*)d_ws;                         // [4096][2048]
  u16* wqkvT = xb    + (size_t)4096 * 2048;        // [3072][2048]
  u16* woT   = wqkvT + (size_t)3072 * 2048;        // [2048][2048]
  u16* QKV   = woT   + (size_t)2048 * 2048;        // [4096][3072]
  u16* Vt    = QKV   + (size_t)4096 * 3072;        // [8][128][2048]
  float* cosT = (float*)(Vt + (size_t)8 * 128 * 2048);  // [2048][64]
  float* sinT = cosT + 2048 * 64;
  u16* AO = xb;  // alias: xb dead after QKV GEMM

  pack_x_kernel<<<8192, 256, 0, stream>>>(x, xb);
  transpose_kernel<<<dim3(64, 64), 256, 0, stream>>>(wq, wqkvT, 2048, 2048);
  transpose_kernel<<<dim3(16, 64), 256, 0, stream>>>(wk, wqkvT + (size_t)2048 * 2048, 2048, 512);
  transpose_kernel<<<dim3(16, 64), 256, 0, stream>>>(wv, wqkvT + (size_t)2560 * 2048, 2048, 512);
  transpose_kernel<<<dim3(64, 64), 256, 0, stream>>>(wo, woT, 2048, 2048);
  rope_tables_kernel<<<512, 256, 0, stream>>>(cosT, sinT);
  gemm_bt_kernel<0><<<dim3(24, 32), 256, 0, stream>>>(xb, wqkvT, (void*)QKV, 4096, 3072, 2048);
  rope_kernel<<<20480, 256, 0, stream>>>(QKV, cosT, sinT);
  v_transpose_kernel<<<dim3(32, 4, 8), 256, 0, stream>>>(QKV, Vt);
  attn_kernel<<<1024, 256, 0, stream>>>(QKV, Vt, AO);
  gemm_bt_kernel<1><<<dim3(16, 32), 256, 0, stream>>>(AO, woT, (void*)out, 4096, 2048, 2048);
}

// Round 11
// 212.900 us; speedup vs baseline: 1.9383x; 1.0010x over previous
//
#include <hip/hip_runtime.h>
#include <cstdint>

typedef unsigned short u16;
typedef __attribute__((ext_vector_type(8))) short bf16x8;
typedef __attribute__((ext_vector_type(4))) float f32x4;

static __device__ __forceinline__ float b2f(u16 u) {
  union { unsigned int i; float f; } v; v.i = ((unsigned int)u) << 16; return v.f;
}
static __device__ __forceinline__ u16 f2b(float f) {
  union { float f; unsigned int i; } v; v.f = f;
  unsigned int r = (v.i + 0x7FFFu + ((v.i >> 16) & 1u)) >> 16;
  return (u16)r;
}
static __device__ __forceinline__ unsigned int cvt_pk_bf16(float lo, float hi) {
  unsigned int r;
  asm("v_cvt_pk_bf16_f32 %0, %1, %2" : "=v"(r) : "v"(lo), "v"(hi));
  return r;
}
static __device__ __forceinline__ void load_lds16(const void* g, void* l) {
  __builtin_amdgcn_global_load_lds((const __attribute__((address_space(1))) void*)g,
                                   (__attribute__((address_space(3))) void*)l, 16, 0, 0);
}

// ---------------- pack x (fp32 -> bf16), 4 elems/thread ----------------
__global__ void pack_x_kernel(const float* __restrict__ x, u16* __restrict__ xb) {
  int idx = blockIdx.x * 256 + threadIdx.x;
  float4 v = ((const float4*)x)[idx];
  unsigned long long pk = (unsigned long long)f2b(v.x)
                        | ((unsigned long long)f2b(v.y) << 16)
                        | ((unsigned long long)f2b(v.z) << 32)
                        | ((unsigned long long)f2b(v.w) << 48);
  ((unsigned long long*)xb)[idx] = pk;
}

// ---------------- transpose fp32 [R][C] -> bf16 [C][R] ----------------
__global__ void transpose_kernel(const float* __restrict__ src, u16* __restrict__ dst,
                                 int R, int C) {
  __shared__ float tile[32][33];
  int tx = threadIdx.x & 31, ty = threadIdx.x >> 5;
  int c0 = blockIdx.x * 32, r0 = blockIdx.y * 32;
#pragma unroll
  for (int i = 0; i < 4; ++i)
    tile[ty + i * 8][tx] = src[(size_t)(r0 + ty + i * 8) * C + c0 + tx];
  __syncthreads();
#pragma unroll
  for (int i = 0; i < 4; ++i)
    dst[(size_t)(c0 + ty + i * 8) * R + r0 + tx] = f2b(tile[tx][ty + i * 8]);
}

// ---------------- V transpose: QKV V-cols -> Vt [b*4+kv][128 d][2048 t] ----------------
__global__ void v_transpose_kernel(const u16* __restrict__ QKV, u16* __restrict__ Vt) {
  __shared__ __align__(16) u16 tile[32][80];
  const int bkv = blockIdx.z;            // 0..7
  const int b = bkv >> 2, kv = bkv & 3;
  const int d0 = blockIdx.y * 32;        // 0..96
  const int t0 = blockIdx.x * 64;        // 0..1984
  const int tid = threadIdx.x;
  const int tr = tid >> 2, dc = tid & 3;
  bf16x8 vv = *(const bf16x8*)(QKV + (size_t)(b * 2048 + t0 + tr) * 3072 + 2560 + kv * 128 + d0 + dc * 8);
#pragma unroll
  for (int e = 0; e < 8; ++e) tile[dc * 8 + e][tr] = (u16)vv[e];
  __syncthreads();
  const int d = tid >> 3, tc = tid & 7;
  *(bf16x8*)(Vt + (size_t)(bkv * 128 + d0 + d) * 2048 + t0 + tc * 8) =
      *(const bf16x8*)&tile[d][tc * 8];
}

// ---------------- RoPE tables: [T][64] cos/sin ----------------
__global__ void rope_tables_kernel(float* __restrict__ cosT, float* __restrict__ sinT) {
  int idx = blockIdx.x * 256 + threadIdx.x;  // T*64
  int t = idx >> 6, i = idx & 63;
  float inv = powf(10000.0f, -(float)i * (1.0f / 64.0f));
  float a = (float)t * inv;
  cosT[idx] = cosf(a);
  sinT[idx] = sinf(a);
}

// ---------------- GEMM: C[M][N] = A[M][K] * BT[N][K]^T  (bf16 in, OUTF=0 bf16 / 1 fp32 out)
// SINGLE-buffered m97 structure (32 KB LDS -> 5 blocks/CU; m132 lesson: occupancy
// beats explicit dbuf at this tile size) + chunk-XOR swizzle (conflicts = 0),
// raw barriers, setprio. Loop: stage -> vmcnt(0) -> barrier -> MFMA -> barrier.
template <int OUTF>
__global__ __launch_bounds__(256) void gemm_bt_kernel(const u16* __restrict__ A,
                                                      const u16* __restrict__ BT,
                                                      void* __restrict__ Cv,
                                                      int M, int N, int K) {
  __shared__ __align__(16) u16 lA[128 * 64];
  __shared__ __align__(16) u16 lB[128 * 64];
  const int tid = threadIdx.x;
  const int wave = tid >> 6, lane = tid & 63;
  const int wr = wave >> 1, wc = wave & 1;
  const int row0 = blockIdx.y * 128, col0 = blockIdx.x * 128;
  f32x4 acc[4][4];
#pragma unroll
  for (int m = 0; m < 4; ++m)
#pragma unroll
    for (int n = 0; n < 4; ++n) acc[m][n] = (f32x4){0.f, 0.f, 0.f, 0.f};
  const int rb = wave * 32;
  const int lrow = lane >> 3;          // 0..7 (row within 8-row stage group)
  const int schk = ((lane & 7) ^ lrow) * 8;  // pre-swizzled source chunk
  const u16* pA = A + (size_t)(row0 + rb + lrow) * K + schk;
  const u16* pB = BT + (size_t)(col0 + rb + lrow) * K + schk;
  const int NT = K >> 6;

  for (int t = 0; t < NT; ++t) {
    const size_t k0 = (size_t)t << 6;
#pragma unroll
    for (int i = 0; i < 4; ++i) {
      load_lds16(pA + k0 + (size_t)i * 8 * K, &lA[(rb + i * 8) * 64]);
      load_lds16(pB + k0 + (size_t)i * 8 * K, &lB[(rb + i * 8) * 64]);
    }
    asm volatile("s_waitcnt vmcnt(0)" ::: "memory");
    __builtin_amdgcn_s_barrier();            // tile ready for all waves
    __builtin_amdgcn_sched_barrier(0);
    __builtin_amdgcn_s_setprio(1);
#pragma unroll
    for (int ks = 0; ks < 2; ++ks) {
      bf16x8 af[4], bfr[4];
      const int sl = ((ks * 4 + (lane >> 4)) ^ (lane & 7)) * 8;  // swizzled read slot
#pragma unroll
      for (int m = 0; m < 4; ++m)
        af[m] = *(const bf16x8*)&lA[(wr * 64 + m * 16 + (lane & 15)) * 64 + sl];
#pragma unroll
      for (int n = 0; n < 4; ++n)
        bfr[n] = *(const bf16x8*)&lB[(wc * 64 + n * 16 + (lane & 15)) * 64 + sl];
#pragma unroll
      for (int m = 0; m < 4; ++m)
#pragma unroll
        for (int n = 0; n < 4; ++n)
          acc[m][n] = __builtin_amdgcn_mfma_f32_16x16x32_bf16(af[m], bfr[n], acc[m][n], 0, 0, 0);
    }
    __builtin_amdgcn_s_setprio(0);
    __builtin_amdgcn_sched_barrier(0);
    __builtin_amdgcn_s_barrier();            // all waves done reading before restage
  }
  const int rbase = row0 + wr * 64 + ((lane >> 4) << 2);
  const int cbase = col0 + wc * 64 + (lane & 15);
#pragma unroll
  for (int m = 0; m < 4; ++m)
#pragma unroll
    for (int n = 0; n < 4; ++n)
#pragma unroll
      for (int j = 0; j < 4; ++j) {
        size_t off = (size_t)(rbase + m * 16 + j) * N + cbase + n * 16;
        if (OUTF == 0) ((u16*)Cv)[off] = f2b(acc[m][n][j]);
        else           ((float*)Cv)[off] = acc[m][n][j];
      }
}

// ---------------- RoPE in-place on Q,K columns of QKV [4096][3072] ----------------
__global__ void rope_kernel(u16* __restrict__ QKV, const float* __restrict__ cosT,
                            const float* __restrict__ sinT) {
  int idx = blockIdx.x * 256 + threadIdx.x;  // 4096*1280
  int row = idx / 1280;
  int rem = idx - row * 1280;
  int t = row & 2047;
  int i = rem & 63;
  int col;
  if (rem < 1024) col = (rem >> 6) * 128 + 2 * i;
  else { int r2 = rem - 1024; col = 2048 + (r2 >> 6) * 128 + 2 * i; }
  float c = cosT[t * 64 + i], s = sinT[t * 64 + i];
  size_t o = (size_t)row * 3072 + col;
  float x1 = b2f(QKV[o]), x2 = b2f(QKV[o + 1]);
  QKV[o]     = f2b(x1 * c - x2 * s);
  QKV[o + 1] = f2b(x1 * s + x2 * c);
}

// ---------------- fused SWA+meta GQA attention, 4-wave QBLK=64, swapped QK^T ----
// Single-buffered K/V (LDS ~41 KB -> 3 blocks/CU), heavy-first qt ordering,
// interior-tile mask skip, cvt_pk packed P-writes. (unchanged from round 10)
__global__ __launch_bounds__(256) void attn_kernel(const u16* __restrict__ QKV,
                                                   const u16* __restrict__ Vt,
                                                   u16* __restrict__ AO) {
  __shared__ __align__(16) u16 lK[64 * 128];      // [key][dh swz]  16KB
  __shared__ __align__(16) u16 lV[128 * 64];      // [dh][key swz]  16KB
  __shared__ __align__(16) u16 lP[4][16 * 70];    // per-wave P [q][key], stride 70
  const int tid = threadIdx.x, wave = tid >> 6, lane = tid & 63;
  const int lid = blockIdx.x;
  const int g = lid & 7;                 // (b,kv) -> same-XCD L2 affinity
  const int b = g >> 2, kv = g & 3;
  const int h = kv * 4 + ((lid >> 3) & 3);
  const int qt = 31 - (lid >> 5);        // heavy blocks (large qt) first
  const int q0 = qt * 64;
  const int qw = q0 + wave * 16;
  const size_t rowbase = (size_t)(b * 2048) * 3072;
  const u16* Qb = QKV + rowbase + h * 128;
  const u16* Kb = QKV + rowbase + 2048 + kv * 128;
  const u16* Vb = Vt + (size_t)g * 128 * 2048;

  bf16x8 qf[4];
  {
    const u16* qs = Qb + (size_t)(qw + (lane & 15)) * 3072 + (lane >> 4) * 8;
#pragma unroll
    for (int s = 0; s < 4; ++s) qf[s] = *(const bf16x8*)(qs + s * 32);
  }
  f32x4 oacc[8];
#pragma unroll
  for (int n = 0; n < 8; ++n) oacc[n] = (f32x4){0.f, 0.f, 0.f, 0.f};
  float m_run = -1e30f, l_run = 0.f;

  const int kt_lo = (q0 > 1023) ? ((q0 - 1023) >> 6) : 0;
  const int nt = (qt - kt_lo + 1) + (kt_lo > 0 ? 1 : 0);

  auto stageK = [&](int kb) {
#pragma unroll
    for (int p = 0; p < 4; ++p) {
      const int rr = p * 4 + (lane >> 4);
      const int sc_ = ((lane & 15) ^ (rr & 7)) * 8;
      load_lds16(Kb + (size_t)(kb + wave * 16 + rr) * 3072 + sc_,
                 &lK[(wave * 16 + p * 4) * 128]);
    }
  };
  auto stageV = [&](int kb) {
#pragma unroll
    for (int p = 0; p < 4; ++p) {
      const int d = wave * 32 + p * 8 + (lane >> 3);
      const int sc_ = ((lane & 7) ^ (lane >> 3)) * 8;
      load_lds16(Vb + (size_t)d * 2048 + kb + sc_,
                 &lV[(wave * 32 + p * 8) * 64]);
    }
  };

  const int qmine = qw + (lane & 15);
  for (int it = 0; it < nt; ++it) {
    const int kt = (kt_lo > 0) ? (it == 0 ? 0 : kt_lo + it - 1) : it;
    const int kb = kt * 64;
    // single-buffer stage: issue, drain own loads, barrier -> tile ready
    stageK(kb);
    stageV(kb);
    asm volatile("s_waitcnt vmcnt(0)" ::: "memory");
    __builtin_amdgcn_s_barrier();
    __builtin_amdgcn_sched_barrier(0);

    // S^T = K Q^T: D col=lane&15=q, row=(lane>>4)*4+j (+ct*16)
    f32x4 sc[4];
    __builtin_amdgcn_s_setprio(1);
#pragma unroll
    for (int ct = 0; ct < 4; ++ct) {
      f32x4 s = (f32x4){0.f, 0.f, 0.f, 0.f};
      const int kr = ct * 16 + (lane & 15);
#pragma unroll
      for (int ss = 0; ss < 4; ++ss) {
        const int ksl = (ss * 4 + (lane >> 4)) ^ (lane & 7);
        bf16x8 kf = *(const bf16x8*)&lK[kr * 128 + ksl * 8];
        s = __builtin_amdgcn_mfma_f32_16x16x32_bf16(kf, qf[ss], s, 0, 0, 0);
      }
      sc[ct] = s;
    }
    __builtin_amdgcn_s_setprio(0);

    const float scale = 0.08838834764831845f;  // 1/sqrt(128)
    // interior tiles: all (q,key) pairs in-window -> scale only, no mask ops
    const bool nomask = (kb + 63 <= qw) && (qw + 15 - kb <= 1023);
    if (nomask) {
#pragma unroll
      for (int ct = 0; ct < 4; ++ct)
#pragma unroll
        for (int j = 0; j < 4; ++j)
          sc[ct][j] *= scale;
    } else {
#pragma unroll
      for (int ct = 0; ct < 4; ++ct) {
        const int kbase = kb + ct * 16 + ((lane >> 4) << 2);
#pragma unroll
        for (int j = 0; j < 4; ++j) {
          const int key = kbase + j;
          float sv = sc[ct][j] * scale;
          bool ok = (key < 16) || (key <= qmine && (qmine - key) < 1024);
          sc[ct][j] = ok ? sv : -1e30f;
        }
      }
    }
    // row max: in-register tree + 2 cross-group shfl
    float mt = sc[0][0];
#pragma unroll
    for (int ct = 0; ct < 4; ++ct)
#pragma unroll
      for (int j = 0; j < 4; ++j) mt = fmaxf(mt, sc[ct][j]);
    mt = fmaxf(mt, __shfl_xor(mt, 16));
    mt = fmaxf(mt, __shfl_xor(mt, 32));
    const float mn = fmaxf(m_run, mt);
    const float alpha = __expf(m_run - mn);
    m_run = mn;
    float rs = 0.f;
#pragma unroll
    for (int ct = 0; ct < 4; ++ct)
#pragma unroll
      for (int j = 0; j < 4; ++j) {
        sc[ct][j] = __expf(sc[ct][j] - mn);
        rs += sc[ct][j];
      }
    rs += __shfl_xor(rs, 16);
    rs += __shfl_xor(rs, 32);
    l_run = l_run * alpha + rs;

    // broadcast alpha to the q-rows this lane accumulates in oacc
    float abc[4];
#pragma unroll
    for (int j = 0; j < 4; ++j)
      abc[j] = __shfl(alpha, ((lane >> 4) << 2) + j, 16);
#pragma unroll
    for (int n = 0; n < 8; ++n)
#pragma unroll
      for (int j = 0; j < 4; ++j)
        oacc[n][j] *= abc[j];

    // packed P write: cvt_pk pairs -> b32 stores; layout == scalar path
    u16* Pw = &lP[wave][0];
    const int pb = (lane & 15) * 70 + ((lane >> 4) << 2);
#pragma unroll
    for (int ct = 0; ct < 4; ++ct) {
      unsigned int w0 = cvt_pk_bf16(sc[ct][0], sc[ct][1]);
      unsigned int w1 = cvt_pk_bf16(sc[ct][2], sc[ct][3]);
      *(unsigned int*)&Pw[pb + ct * 16]     = w0;
      *(unsigned int*)&Pw[pb + ct * 16 + 2] = w1;
    }

    __builtin_amdgcn_s_setprio(1);
#pragma unroll
    for (int kss = 0; kss < 2; ++kss) {
      bf16x8 pa = *(const bf16x8*)&Pw[(lane & 15) * 70 + kss * 32 + (lane >> 4) * 8];
#pragma unroll
      for (int n = 0; n < 8; ++n) {
        const int vrow = n * 16 + (lane & 15);
        const int vsl = (kss * 4 + (lane >> 4)) ^ (lane & 7);
        bf16x8 vf = *(const bf16x8*)&lV[vrow * 64 + vsl * 8];
        oacc[n] = __builtin_amdgcn_mfma_f32_16x16x32_bf16(pa, vf, oacc[n], 0, 0, 0);
      }
    }
    __builtin_amdgcn_s_setprio(0);
    __builtin_amdgcn_sched_barrier(0);
    __builtin_amdgcn_s_barrier();          // all waves done reading lK/lV before restage
  }
  const float linv = 1.0f / l_run;
  const int qrb = qw + ((lane >> 4) << 2);
#pragma unroll
  for (int j = 0; j < 4; ++j) {
    const float inv = __shfl(linv, ((lane >> 4) << 2) + j, 16);
    const size_t rowo = (size_t)(b * 2048 + qrb + j) * 2048 + h * 128;
#pragma unroll
    for (int n = 0; n < 8; ++n)
      AO[rowo + n * 16 + (lane & 15)] = f2b(oacc[n][j] * inv);
  }
}

extern "C" void kernel_launch(void* const* d_in, const int* in_sizes, int n_in,
                              void* d_out, int out_size, void* d_ws, size_t ws_size,
                              hipStream_t stream) {
  (void)in_sizes; (void)n_in; (void)out_size; (void)ws_size;
  const float* x  = (const float*)d_in[0];
  const float* wq = (const float*)d_in[1];
  const float* wk = (const float*)d_in[2];
  const float* wv = (const float*)d_in[3];
  const float* wo = (const float*)d_in[4];
  float* out = (float*)d_out;

  // workspace carve (~68 MB)
  u16* xb    = (u16*)d_ws;                         // [4096][2048]
  u16* wqkvT = xb    + (size_t)4096 * 2048;        // [3072][2048]
  u16* woT   = wqkvT + (size_t)3072 * 2048;        // [2048][2048]
  u16* QKV   = woT   + (size_t)2048 * 2048;        // [4096][3072]
  u16* Vt    = QKV   + (size_t)4096 * 3072;        // [8][128][2048]
  float* cosT = (float*)(Vt + (size_t)8 * 128 * 2048);  // [2048][64]
  float* sinT = cosT + 2048 * 64;
  u16* AO = xb;  // alias: xb dead after QKV GEMM

  pack_x_kernel<<<8192, 256, 0, stream>>>(x, xb);
  transpose_kernel<<<dim3(64, 64), 256, 0, stream>>>(wq, wqkvT, 2048, 2048);
  transpose_kernel<<<dim3(16, 64), 256, 0, stream>>>(wk, wqkvT + (size_t)2048 * 2048, 2048, 512);
  transpose_kernel<<<dim3(16, 64), 256, 0, stream>>>(wv, wqkvT + (size_t)2560 * 2048, 2048, 512);
  transpose_kernel<<<dim3(64, 64), 256, 0, stream>>>(wo, woT, 2048, 2048);
  rope_tables_kernel<<<512, 256, 0, stream>>>(cosT, sinT);
  gemm_bt_kernel<0><<<dim3(24, 32), 256, 0, stream>>>(xb, wqkvT, (void*)QKV, 4096, 3072, 2048);
  rope_kernel<<<20480, 256, 0, stream>>>(QKV, cosT, sinT);
  v_transpose_kernel<<<dim3(32, 4, 8), 256, 0, stream>>>(QKV, Vt);
  attn_kernel<<<1024, 256, 0, stream>>>(QKV, Vt, AO);
  gemm_bt_kernel<1><<<dim3(16, 32), 256, 0, stream>>>(AO, woT, (void*)out, 4096, 2048, 2048);
}

// Round 16
// 205.012 us; speedup vs baseline: 2.0128x; 1.0385x over previous
//
#include <hip/hip_runtime.h>
#include <cstdint>

typedef unsigned short u16;
typedef __attribute__((ext_vector_type(8))) short bf16x8;
typedef __attribute__((ext_vector_type(4))) float f32x4;

static __device__ __forceinline__ float b2f(u16 u) {
  union { unsigned int i; float f; } v; v.i = ((unsigned int)u) << 16; return v.f;
}
static __device__ __forceinline__ u16 f2b(float f) {
  union { float f; unsigned int i; } v; v.f = f;
  unsigned int r = (v.i + 0x7FFFu + ((v.i >> 16) & 1u)) >> 16;
  return (u16)r;
}
static __device__ __forceinline__ unsigned int cvt_pk_bf16(float lo, float hi) {
  unsigned int r;
  asm("v_cvt_pk_bf16_f32 %0, %1, %2" : "=v"(r) : "v"(lo), "v"(hi));
  return r;
}
static __device__ __forceinline__ void load_lds16(const void* g, void* l) {
  __builtin_amdgcn_global_load_lds((const __attribute__((address_space(1))) void*)g,
                                   (__attribute__((address_space(3))) void*)l, 16, 0, 0);
}

// ---------------- pack x (fp32 -> bf16), 4 elems/thread ----------------
__global__ void pack_x_kernel(const float* __restrict__ x, u16* __restrict__ xb) {
  int idx = blockIdx.x * 256 + threadIdx.x;
  float4 v = ((const float4*)x)[idx];
  unsigned long long pk = (unsigned long long)f2b(v.x)
                        | ((unsigned long long)f2b(v.y) << 16)
                        | ((unsigned long long)f2b(v.z) << 32)
                        | ((unsigned long long)f2b(v.w) << 48);
  ((unsigned long long*)xb)[idx] = pk;
}

// ---------------- transpose fp32 [R][C] -> bf16 [C][R] ----------------
__global__ void transpose_kernel(const float* __restrict__ src, u16* __restrict__ dst,
                                 int R, int C) {
  __shared__ float tile[32][33];
  int tx = threadIdx.x & 31, ty = threadIdx.x >> 5;
  int c0 = blockIdx.x * 32, r0 = blockIdx.y * 32;
#pragma unroll
  for (int i = 0; i < 4; ++i)
    tile[ty + i * 8][tx] = src[(size_t)(r0 + ty + i * 8) * C + c0 + tx];
  __syncthreads();
#pragma unroll
  for (int i = 0; i < 4; ++i)
    dst[(size_t)(c0 + ty + i * 8) * R + r0 + tx] = f2b(tile[tx][ty + i * 8]);
}

// ---------------- V transpose: QKV V-cols -> Vt [b*4+kv][128 d][2048 t] ----------------
__global__ void v_transpose_kernel(const u16* __restrict__ QKV, u16* __restrict__ Vt) {
  __shared__ __align__(16) u16 tile[32][80];
  const int bkv = blockIdx.z;            // 0..7
  const int b = bkv >> 2, kv = bkv & 3;
  const int d0 = blockIdx.y * 32;        // 0..96
  const int t0 = blockIdx.x * 64;        // 0..1984
  const int tid = threadIdx.x;
  const int tr = tid >> 2, dc = tid & 3;
  bf16x8 vv = *(const bf16x8*)(QKV + (size_t)(b * 2048 + t0 + tr) * 3072 + 2560 + kv * 128 + d0 + dc * 8);
#pragma unroll
  for (int e = 0; e < 8; ++e) tile[dc * 8 + e][tr] = (u16)vv[e];
  __syncthreads();
  const int d = tid >> 3, tc = tid & 7;
  *(bf16x8*)(Vt + (size_t)(bkv * 128 + d0 + d) * 2048 + t0 + tc * 8) =
      *(const bf16x8*)&tile[d][tc * 8];
}

// ---------------- RoPE tables: [T][64] cos/sin ----------------
__global__ void rope_tables_kernel(float* __restrict__ cosT, float* __restrict__ sinT) {
  int idx = blockIdx.x * 256 + threadIdx.x;  // T*64
  int t = idx >> 6, i = idx & 63;
  float inv = powf(10000.0f, -(float)i * (1.0f / 64.0f));
  float a = (float)t * inv;
  cosT[idx] = cosf(a);
  sinT[idx] = sinf(a);
}

// ---------------- GEMM: C[M][N] = A[M][K] * BT[N][K]^T  (bf16 in, OUTF=0 bf16 / 1 fp32 out)
// SINGLE-buffered m97 structure (32 KB LDS -> 5 blocks/CU) + chunk-XOR swizzle
// (conflicts = 0), raw barriers, setprio. (unchanged from round 11)
template <int OUTF>
__global__ __launch_bounds__(256) void gemm_bt_kernel(const u16* __restrict__ A,
                                                      const u16* __restrict__ BT,
                                                      void* __restrict__ Cv,
                                                      int M, int N, int K) {
  __shared__ __align__(16) u16 lA[128 * 64];
  __shared__ __align__(16) u16 lB[128 * 64];
  const int tid = threadIdx.x;
  const int wave = tid >> 6, lane = tid & 63;
  const int wr = wave >> 1, wc = wave & 1;
  const int row0 = blockIdx.y * 128, col0 = blockIdx.x * 128;
  f32x4 acc[4][4];
#pragma unroll
  for (int m = 0; m < 4; ++m)
#pragma unroll
    for (int n = 0; n < 4; ++n) acc[m][n] = (f32x4){0.f, 0.f, 0.f, 0.f};
  const int rb = wave * 32;
  const int lrow = lane >> 3;          // 0..7 (row within 8-row stage group)
  const int schk = ((lane & 7) ^ lrow) * 8;  // pre-swizzled source chunk
  const u16* pA = A + (size_t)(row0 + rb + lrow) * K + schk;
  const u16* pB = BT + (size_t)(col0 + rb + lrow) * K + schk;
  const int NT = K >> 6;

  for (int t = 0; t < NT; ++t) {
    const size_t k0 = (size_t)t << 6;
#pragma unroll
    for (int i = 0; i < 4; ++i) {
      load_lds16(pA + k0 + (size_t)i * 8 * K, &lA[(rb + i * 8) * 64]);
      load_lds16(pB + k0 + (size_t)i * 8 * K, &lB[(rb + i * 8) * 64]);
    }
    asm volatile("s_waitcnt vmcnt(0)" ::: "memory");
    __builtin_amdgcn_s_barrier();            // tile ready for all waves
    __builtin_amdgcn_sched_barrier(0);
    __builtin_amdgcn_s_setprio(1);
#pragma unroll
    for (int ks = 0; ks < 2; ++ks) {
      bf16x8 af[4], bfr[4];
      const int sl = ((ks * 4 + (lane >> 4)) ^ (lane & 7)) * 8;  // swizzled read slot
#pragma unroll
      for (int m = 0; m < 4; ++m)
        af[m] = *(const bf16x8*)&lA[(wr * 64 + m * 16 + (lane & 15)) * 64 + sl];
#pragma unroll
      for (int n = 0; n < 4; ++n)
        bfr[n] = *(const bf16x8*)&lB[(wc * 64 + n * 16 + (lane & 15)) * 64 + sl];
#pragma unroll
      for (int m = 0; m < 4; ++m)
#pragma unroll
        for (int n = 0; n < 4; ++n)
          acc[m][n] = __builtin_amdgcn_mfma_f32_16x16x32_bf16(af[m], bfr[n], acc[m][n], 0, 0, 0);
    }
    __builtin_amdgcn_s_setprio(0);
    __builtin_amdgcn_sched_barrier(0);
    __builtin_amdgcn_s_barrier();            // all waves done reading before restage
  }
  const int rbase = row0 + wr * 64 + ((lane >> 4) << 2);
  const int cbase = col0 + wc * 64 + (lane & 15);
#pragma unroll
  for (int m = 0; m < 4; ++m)
#pragma unroll
    for (int n = 0; n < 4; ++n)
#pragma unroll
      for (int j = 0; j < 4; ++j) {
        size_t off = (size_t)(rbase + m * 16 + j) * N + cbase + n * 16;
        if (OUTF == 0) ((u16*)Cv)[off] = f2b(acc[m][n][j]);
        else           ((float*)Cv)[off] = acc[m][n][j];
      }
}

// ---------------- RoPE in-place on Q,K columns of QKV [4096][3072] ----------------
// (round-11 version: NO scale folding — scale applied in attn)
__global__ void rope_kernel(u16* __restrict__ QKV, const float* __restrict__ cosT,
                            const float* __restrict__ sinT) {
  int idx = blockIdx.x * 256 + threadIdx.x;  // 4096*1280
  int row = idx / 1280;
  int rem = idx - row * 1280;
  int t = row & 2047;
  int i = rem & 63;
  int col;
  if (rem < 1024) col = (rem >> 6) * 128 + 2 * i;
  else { int r2 = rem - 1024; col = 2048 + (r2 >> 6) * 128 + 2 * i; }
  float c = cosT[t * 64 + i], s = sinT[t * 64 + i];
  size_t o = (size_t)row * 3072 + col;
  float x1 = b2f(QKV[o]), x2 = b2f(QKV[o + 1]);
  QKV[o]     = f2b(x1 * c - x2 * s);
  QKV[o + 1] = f2b(x1 * s + x2 * c);
}

// ---------------- fused SWA+meta GQA attention, 4-wave QBLK=64, swapped QK^T ----
// EXACT round-11 structure (last known-good) with ONE constant change:
// lP row stride 70 -> 72 elements (144 B). Identical index mapping; rows are
// now 16B-aligned so the bf16x8 P-reads are aligned ds_read_b128 (stride-70
// rows put most reads on unaligned 16B boundaries -> compiler splits them).
// Byte stride 144 -> bank stride 4 -> 2-way aliasing (free, m136).
__global__ __launch_bounds__(256) void attn_kernel(const u16* __restrict__ QKV,
                                                   const u16* __restrict__ Vt,
                                                   u16* __restrict__ AO) {
  __shared__ __align__(16) u16 lK[64 * 128];      // [key][dh swz]  16KB
  __shared__ __align__(16) u16 lV[128 * 64];      // [dh][key swz]  16KB
  __shared__ __align__(16) u16 lP[4][16 * 72];    // per-wave P [q][key], stride 72
  const int tid = threadIdx.x, wave = tid >> 6, lane = tid & 63;
  const int lid = blockIdx.x;
  const int g = lid & 7;                 // (b,kv) -> same-XCD L2 affinity
  const int b = g >> 2, kv = g & 3;
  const int h = kv * 4 + ((lid >> 3) & 3);
  const int qt = 31 - (lid >> 5);        // heavy blocks (large qt) first
  const int q0 = qt * 64;
  const int qw = q0 + wave * 16;
  const size_t rowbase = (size_t)(b * 2048) * 3072;
  const u16* Qb = QKV + rowbase + h * 128;
  const u16* Kb = QKV + rowbase + 2048 + kv * 128;
  const u16* Vb = Vt + (size_t)g * 128 * 2048;

  bf16x8 qf[4];
  {
    const u16* qs = Qb + (size_t)(qw + (lane & 15)) * 3072 + (lane >> 4) * 8;
#pragma unroll
    for (int s = 0; s < 4; ++s) qf[s] = *(const bf16x8*)(qs + s * 32);
  }
  f32x4 oacc[8];
#pragma unroll
  for (int n = 0; n < 8; ++n) oacc[n] = (f32x4){0.f, 0.f, 0.f, 0.f};
  float m_run = -1e30f, l_run = 0.f;

  const int kt_lo = (q0 > 1023) ? ((q0 - 1023) >> 6) : 0;
  const int nt = (qt - kt_lo + 1) + (kt_lo > 0 ? 1 : 0);

  auto stageK = [&](int kb) {
#pragma unroll
    for (int p = 0; p < 4; ++p) {
      const int rr = p * 4 + (lane >> 4);
      const int sc_ = ((lane & 15) ^ (rr & 7)) * 8;
      load_lds16(Kb + (size_t)(kb + wave * 16 + rr) * 3072 + sc_,
                 &lK[(wave * 16 + p * 4) * 128]);
    }
  };
  auto stageV = [&](int kb) {
#pragma unroll
    for (int p = 0; p < 4; ++p) {
      const int d = wave * 32 + p * 8 + (lane >> 3);
      const int sc_ = ((lane & 7) ^ (lane >> 3)) * 8;
      load_lds16(Vb + (size_t)d * 2048 + kb + sc_,
                 &lV[(wave * 32 + p * 8) * 64]);
    }
  };

  const int qmine = qw + (lane & 15);
  for (int it = 0; it < nt; ++it) {
    const int kt = (kt_lo > 0) ? (it == 0 ? 0 : kt_lo + it - 1) : it;
    const int kb = kt * 64;
    // single-buffer stage: issue, drain own loads, barrier -> tile ready
    stageK(kb);
    stageV(kb);
    asm volatile("s_waitcnt vmcnt(0)" ::: "memory");
    __builtin_amdgcn_s_barrier();
    __builtin_amdgcn_sched_barrier(0);

    // S^T = K Q^T: D col=lane&15=q, row=(lane>>4)*4+j (+ct*16)
    f32x4 sc[4];
    __builtin_amdgcn_s_setprio(1);
#pragma unroll
    for (int ct = 0; ct < 4; ++ct) {
      f32x4 s = (f32x4){0.f, 0.f, 0.f, 0.f};
      const int kr = ct * 16 + (lane & 15);
#pragma unroll
      for (int ss = 0; ss < 4; ++ss) {
        const int ksl = (ss * 4 + (lane >> 4)) ^ (lane & 7);
        bf16x8 kf = *(const bf16x8*)&lK[kr * 128 + ksl * 8];
        s = __builtin_amdgcn_mfma_f32_16x16x32_bf16(kf, qf[ss], s, 0, 0, 0);
      }
      sc[ct] = s;
    }
    __builtin_amdgcn_s_setprio(0);

    const float scale = 0.08838834764831845f;  // 1/sqrt(128)
    // interior tiles: all (q,key) pairs in-window -> scale only, no mask ops
    const bool nomask = (kb + 63 <= qw) && (qw + 15 - kb <= 1023);
    if (nomask) {
#pragma unroll
      for (int ct = 0; ct < 4; ++ct)
#pragma unroll
        for (int j = 0; j < 4; ++j)
          sc[ct][j] *= scale;
    } else {
#pragma unroll
      for (int ct = 0; ct < 4; ++ct) {
        const int kbase = kb + ct * 16 + ((lane >> 4) << 2);
#pragma unroll
        for (int j = 0; j < 4; ++j) {
          const int key = kbase + j;
          float sv = sc[ct][j] * scale;
          bool ok = (key < 16) || (key <= qmine && (qmine - key) < 1024);
          sc[ct][j] = ok ? sv : -1e30f;
        }
      }
    }
    // row max: in-register tree + 2 cross-group shfl
    float mt = sc[0][0];
#pragma unroll
    for (int ct = 0; ct < 4; ++ct)
#pragma unroll
      for (int j = 0; j < 4; ++j) mt = fmaxf(mt, sc[ct][j]);
    mt = fmaxf(mt, __shfl_xor(mt, 16));
    mt = fmaxf(mt, __shfl_xor(mt, 32));
    const float mn = fmaxf(m_run, mt);
    const float alpha = __expf(m_run - mn);
    m_run = mn;
    float rs = 0.f;
#pragma unroll
    for (int ct = 0; ct < 4; ++ct)
#pragma unroll
      for (int j = 0; j < 4; ++j) {
        sc[ct][j] = __expf(sc[ct][j] - mn);
        rs += sc[ct][j];
      }
    rs += __shfl_xor(rs, 16);
    rs += __shfl_xor(rs, 32);
    l_run = l_run * alpha + rs;

    // broadcast alpha to the q-rows this lane accumulates in oacc
    float abc[4];
#pragma unroll
    for (int j = 0; j < 4; ++j)
      abc[j] = __shfl(alpha, ((lane >> 4) << 2) + j, 16);
#pragma unroll
    for (int n = 0; n < 8; ++n)
#pragma unroll
      for (int j = 0; j < 4; ++j)
        oacc[n][j] *= abc[j];

    // packed P write: cvt_pk pairs -> b32 stores; layout == scalar path
    u16* Pw = &lP[wave][0];
    const int pb = (lane & 15) * 72 + ((lane >> 4) << 2);
#pragma unroll
    for (int ct = 0; ct < 4; ++ct) {
      unsigned int w0 = cvt_pk_bf16(sc[ct][0], sc[ct][1]);
      unsigned int w1 = cvt_pk_bf16(sc[ct][2], sc[ct][3]);
      *(unsigned int*)&Pw[pb + ct * 16]     = w0;
      *(unsigned int*)&Pw[pb + ct * 16 + 2] = w1;
    }

    __builtin_amdgcn_s_setprio(1);
#pragma unroll
    for (int kss = 0; kss < 2; ++kss) {
      bf16x8 pa = *(const bf16x8*)&Pw[(lane & 15) * 72 + kss * 32 + (lane >> 4) * 8];
#pragma unroll
      for (int n = 0; n < 8; ++n) {
        const int vrow = n * 16 + (lane & 15);
        const int vsl = (kss * 4 + (lane >> 4)) ^ (lane & 7);
        bf16x8 vf = *(const bf16x8*)&lV[vrow * 64 + vsl * 8];
        oacc[n] = __builtin_amdgcn_mfma_f32_16x16x32_bf16(pa, vf, oacc[n], 0, 0, 0);
      }
    }
    __builtin_amdgcn_s_setprio(0);
    __builtin_amdgcn_sched_barrier(0);
    __builtin_amdgcn_s_barrier();          // all waves done reading lK/lV before restage
  }
  const float linv = 1.0f / l_run;
  const int qrb = qw + ((lane >> 4) << 2);
#pragma unroll
  for (int j = 0; j < 4; ++j) {
    const float inv = __shfl(linv, ((lane >> 4) << 2) + j, 16);
    const size_t rowo = (size_t)(b * 2048 + qrb + j) * 2048 + h * 128;
#pragma unroll
    for (int n = 0; n < 8; ++n)
      AO[rowo + n * 16 + (lane & 15)] = f2b(oacc[n][j] * inv);
  }
}

extern "C" void kernel_launch(void* const* d_in, const int* in_sizes, int n_in,
                              void* d_out, int out_size, void* d_ws, size_t ws_size,
                              hipStream_t stream) {
  (void)in_sizes; (void)n_in; (void)out_size; (void)ws_size;
  const float* x  = (const float*)d_in[0];
  const float* wq = (const float*)d_in[1];
  const float* wk = (const float*)d_in[2];
  const float* wv = (const float*)d_in[3];
  const float* wo = (const float*)d_in[4];
  float* out = (float*)d_out;

  // workspace carve (~68 MB)
  u16* xb    = (u16*)d_ws;                         // [4096][2048]
  u16* wqkvT = xb    + (size_t)4096 * 2048;        // [3072][2048]
  u16* woT   = wqkvT + (size_t)3072 * 2048;        // [2048][2048]
  u16* QKV   = woT   + (size_t)2048 * 2048;        // [4096][3072]
  u16* Vt    = QKV   + (size_t)4096 * 3072;        // [8][128][2048]
  float* cosT = (float*)(Vt + (size_t)8 * 128 * 2048);  // [2048][64]
  float* sinT = cosT + 2048 * 64;
  u16* AO = xb;  // alias: xb dead after QKV GEMM

  pack_x_kernel<<<8192, 256, 0, stream>>>(x, xb);
  transpose_kernel<<<dim3(64, 64), 256, 0, stream>>>(wq, wqkvT, 2048, 2048);
  transpose_kernel<<<dim3(16, 64), 256, 0, stream>>>(wk, wqkvT + (size_t)2048 * 2048, 2048, 512);
  transpose_kernel<<<dim3(16, 64), 256, 0, stream>>>(wv, wqkvT + (size_t)2560 * 2048, 2048, 512);
  transpose_kernel<<<dim3(64, 64), 256, 0, stream>>>(wo, woT, 2048, 2048);
  rope_tables_kernel<<<512, 256, 0, stream>>>(cosT, sinT);
  gemm_bt_kernel<0><<<dim3(24, 32), 256, 0, stream>>>(xb, wqkvT, (void*)QKV, 4096, 3072, 2048);
  rope_kernel<<<20480, 256, 0, stream>>>(QKV, cosT, sinT);
  v_transpose_kernel<<<dim3(32, 4, 8), 256, 0, stream>>>(QKV, Vt);
  attn_kernel<<<1024, 256, 0, stream>>>(QKV, Vt, AO);
  gemm_bt_kernel<1><<<dim3(16, 32), 256, 0, stream>>>(AO, woT, (void*)out, 4096, 2048, 2048);
}